// Round 1
// baseline (1657.033 us; speedup 1.0000x reference)
//
#include <hip/hip_runtime.h>
#include <hip/hip_bf16.h>
#include <math.h>

#define B_  32
#define L_  1024
#define CIN 3
#define DM  256
#define DI  512
#define NST 16
#define NH  8
#define NC  10
#define M_TOT (B_*L_)

static __device__ __forceinline__ float sigmoidf_(float x) {
    return 1.0f / (1.0f + __expf(-x));
}

// ---------------- K1: conv embedding + positional encoding ----------------
// x[b,l,d] = sum_{i,k} x_enc[b, clamp(l+k-1), i] * w[d,i,k] + pe[l,d]
__global__ __launch_bounds__(256) void k_embed(const float* __restrict__ xe,
        const float* __restrict__ w, float* __restrict__ x) {
    int bl = blockIdx.x;
    int l = bl & (L_-1);
    int b = bl >> 10;
    int d = threadIdx.x;
    const float* xb = xe + (size_t)b * L_ * CIN;
    int t0 = l > 0 ? l-1 : 0;
    int t2 = l < L_-1 ? l+1 : L_-1;
    const float* w3 = w + d*9;
    float acc = 0.f;
    #pragma unroll
    for (int i = 0; i < 3; ++i) {
        acc += xb[t0*3+i] * w3[i*3+0];
        acc += xb[l *3+i] * w3[i*3+1];
        acc += xb[t2*3+i] * w3[i*3+2];
    }
    int j = d >> 1;
    float div = expf((float)(2*j) * (-logf(10000.0f)/(float)DM));
    float ang = (float)l * div;
    acc += (d & 1) ? cosf(ang) : sinf(ang);
    x[(size_t)bl*DM + d] = acc;
}

// ---------------- K2/K7: generic fp32 NT GEMM  C[m,n] = sum_k A[m,k]*W[n,k]
// 128x128 tile, BK=8, 256 threads, 8x8 per thread. Split output at col S
// (cols < S -> O1 row-major M x S ; cols >= S -> O2 row-major M x (N-S)).
#define BM 128
#define BN 128
#define BK 8
__global__ __launch_bounds__(256) void k_gemm_nt(
        const float* __restrict__ A, const float* __restrict__ W,
        float* __restrict__ O1, float* __restrict__ O2,
        int M, int N, int K, int S) {
    __shared__ float As[BK][BM];
    __shared__ float Ws[BK][BN];
    int tid = threadIdx.x;
    int bx = blockIdx.x, by = blockIdx.y;
    int tx = tid & 15, ty = tid >> 4;
    int row0 = by*BM, col0 = bx*BN;
    int lr = tid >> 1;
    int lc = (tid & 1) * 4;
    const float* Ag = A + (size_t)(row0 + lr) * K + lc;
    const float* Wg = W + (size_t)(col0 + lr) * K + lc;
    float acc[8][8];
    #pragma unroll
    for (int i = 0; i < 8; ++i)
        #pragma unroll
        for (int j = 0; j < 8; ++j) acc[i][j] = 0.f;

    for (int k0 = 0; k0 < K; k0 += BK) {
        float4 av = *(const float4*)(Ag + k0);
        float4 wv = *(const float4*)(Wg + k0);
        __syncthreads();
        As[lc+0][lr] = av.x; As[lc+1][lr] = av.y; As[lc+2][lr] = av.z; As[lc+3][lr] = av.w;
        Ws[lc+0][lr] = wv.x; Ws[lc+1][lr] = wv.y; Ws[lc+2][lr] = wv.z; Ws[lc+3][lr] = wv.w;
        __syncthreads();
        #pragma unroll
        for (int k = 0; k < BK; ++k) {
            float4 a0 = *(const float4*)&As[k][ty*8];
            float4 a1 = *(const float4*)&As[k][ty*8+4];
            float4 b0 = *(const float4*)&Ws[k][tx*8];
            float4 b1 = *(const float4*)&Ws[k][tx*8+4];
            float ar[8] = {a0.x,a0.y,a0.z,a0.w,a1.x,a1.y,a1.z,a1.w};
            float br[8] = {b0.x,b0.y,b0.z,b0.w,b1.x,b1.y,b1.z,b1.w};
            #pragma unroll
            for (int i = 0; i < 8; ++i)
                #pragma unroll
                for (int j = 0; j < 8; ++j)
                    acc[i][j] = fmaf(ar[i], br[j], acc[i][j]);
        }
    }
    #pragma unroll
    for (int i = 0; i < 8; ++i) {
        size_t m = row0 + ty*8 + i;
        #pragma unroll
        for (int j = 0; j < 8; j += 4) {
            int n = col0 + tx*8 + j;
            float4 v = make_float4(acc[i][j],acc[i][j+1],acc[i][j+2],acc[i][j+3]);
            if (n < S) *(float4*)(O1 + m*(size_t)S + n) = v;
            else       *(float4*)(O2 + m*(size_t)(N-S) + (n-S)) = v;
        }
    }
}

// ---------------- K3: depthwise causal conv1d (k=4) + bias + silu ----------
__global__ __launch_bounds__(256) void k_conv(const float* __restrict__ xin,
        const float* __restrict__ w, const float* __restrict__ bias,
        float* __restrict__ xc) {
    size_t idx = (size_t)blockIdx.x * 256 + threadIdx.x;  // over M_TOT*DI
    int d = (int)(idx & (DI-1));
    size_t m = idx >> 9;
    int l = (int)(m & (L_-1));
    float acc = bias[d];
    #pragma unroll
    for (int k = 0; k < 4; ++k) {
        int t = l + k - 3;
        if (t >= 0)
            acc = fmaf(xin[idx + ((size_t)(k-3))*DI], w[d*4 + k], acc);
    }
    xc[idx] = acc * sigmoidf_(acc);
}

// ---------------- K4: x_proj  dbl[m,e] = sum_d xc[m,d]*wp[e,d], e<48 -------
__global__ __launch_bounds__(384) void k_xproj(const float* __restrict__ xc,
        const float* __restrict__ wp, float* __restrict__ dbl) {
    __shared__ float ld[8][DI];
    size_t m0 = (size_t)blockIdx.x * 8;
    for (int idx = threadIdx.x; idx < 8*DI; idx += 384)
        ld[idx >> 9][idx & (DI-1)] = xc[m0*DI + idx];
    __syncthreads();
    int t = threadIdx.x;
    int r = t / 48, e = t % 48;
    const float4* a  = (const float4*)&ld[r][0];
    const float4* wv = (const float4*)(wp + (size_t)e*DI);
    float acc = 0.f;
    #pragma unroll 4
    for (int d4 = 0; d4 < DI/4; ++d4) {
        float4 av = a[d4], bv = wv[d4];
        acc += av.x*bv.x + av.y*bv.y + av.z*bv.z + av.w*bv.w;
    }
    dbl[(m0 + r)*48 + e] = acc;
}

// ---------------- K5: dt_proj (K=16) + softplus ----------------------------
__global__ __launch_bounds__(256) void k_dtproj(const float* __restrict__ dbl,
        const float* __restrict__ dtw, const float* __restrict__ dtb,
        float* __restrict__ dt) {
    __shared__ float wl[DI][17];
    __shared__ float rl[32][16];
    size_t m0 = (size_t)blockIdx.x * 32;
    for (int i = threadIdx.x; i < DI*16; i += 256)
        wl[i >> 4][i & 15] = dtw[i];
    for (int i = threadIdx.x; i < 32*16; i += 256)
        rl[i >> 4][i & 15] = dbl[(m0 + (i>>4))*48 + (i & 15)];
    __syncthreads();
    float b0 = dtb[threadIdx.x];
    float b1 = dtb[256 + threadIdx.x];
    for (int mm = 0; mm < 32; ++mm) {
        #pragma unroll
        for (int half = 0; half < 2; ++half) {
            int d = half*256 + threadIdx.x;
            float acc = half ? b1 : b0;
            #pragma unroll
            for (int r = 0; r < 16; ++r)
                acc = fmaf(rl[mm][r], wl[d][r], acc);
            float sp = fmaxf(acc, 0.f) + log1pf(__expf(-fabsf(acc)));
            dt[(m0+mm)*DI + d] = sp;
        }
    }
}

// ---------------- K6: selective scan + D-skip + silu(z) gate (in-place z->y)
__global__ __launch_bounds__(256) void k_scan(const float* __restrict__ dt,
        const float* __restrict__ xc, const float* __restrict__ dbl,
        const float* __restrict__ A_log, const float* __restrict__ Dp,
        float* __restrict__ zy) {
    __shared__ float BC[16][32];   // [t][0..15]=B, [16..31]=C
    int b = blockIdx.x >> 1;
    int d = (blockIdx.x & 1)*256 + threadIdx.x;
    float Av[NST], h[NST];
    #pragma unroll
    for (int n = 0; n < NST; ++n) {
        Av[n] = -expf(A_log[(size_t)d*NST + n]);
        h[n] = 0.f;
    }
    float Dd = Dp[d];
    size_t base = (size_t)b * L_;
    for (int t0 = 0; t0 < L_; t0 += 16) {
        __syncthreads();
        for (int i = threadIdx.x; i < 16*32; i += 256)
            BC[i >> 5][i & 31] = dbl[(base + t0 + (i>>5))*48 + 16 + (i & 31)];
        __syncthreads();
        for (int tt = 0; tt < 16; ++tt) {
            size_t off = (base + t0 + tt)*DI + d;
            float dtv = dt[off];
            float xv  = xc[off];
            float zv  = zy[off];
            float dtx = dtv * xv;
            float y = 0.f;
            #pragma unroll
            for (int n = 0; n < NST; ++n) {
                float dA = __expf(dtv * Av[n]);
                h[n] = fmaf(dA, h[n], dtx * BC[tt][n]);
                y = fmaf(h[n], BC[tt][16+n], y);
            }
            y = (y + xv*Dd) * (zv * sigmoidf_(zv));
            zy[off] = y;
        }
    }
}

// ---------------- K8: LayerNorm + silu (in place) --------------------------
__global__ __launch_bounds__(256) void k_ln(float* __restrict__ m,
        const float* __restrict__ g, const float* __restrict__ bta) {
    __shared__ float sm[4];
    size_t row = blockIdx.x;
    int tid = threadIdx.x;
    float v = m[row*DM + tid];
    float s = v;
    #pragma unroll
    for (int o = 32; o > 0; o >>= 1) s += __shfl_xor(s, o);
    if ((tid & 63) == 0) sm[tid >> 6] = s;
    __syncthreads();
    float mu = (sm[0]+sm[1]+sm[2]+sm[3]) * (1.0f/DM);
    __syncthreads();
    float c = v - mu;
    float s2 = c*c;
    #pragma unroll
    for (int o = 32; o > 0; o >>= 1) s2 += __shfl_xor(s2, o);
    if ((tid & 63) == 0) sm[tid >> 6] = s2;
    __syncthreads();
    float var = (sm[0]+sm[1]+sm[2]+sm[3]) * (1.0f/DM);
    float o = c * (1.0f/sqrtf(var + 1e-5f)) * g[tid] + bta[tid];
    m[row*DM + tid] = o * sigmoidf_(o);
}

// ---------------- K9a: per-(b,l) attn-max + class logits -------------------
__global__ __launch_bounds__(64) void k_heads(const float* __restrict__ m,
        const float* __restrict__ aw, const float* __restrict__ ab,
        const float* __restrict__ ow, float* __restrict__ smax,
        float* __restrict__ logits) {
    int bl = blockIdx.x;
    int lane = threadIdx.x;
    const float* mr = m + (size_t)bl*DM;
    float v0 = mr[lane], v1 = mr[lane+64], v2 = mr[lane+128], v3 = mr[lane+192];
    float sm = -1e30f;
    for (int j = 0; j < NH+NC; ++j) {
        const float* wr = (j < NH) ? (aw + j*DM) : (ow + (j-NH)*DM);
        float acc = v0*wr[lane] + v1*wr[lane+64] + v2*wr[lane+128] + v3*wr[lane+192];
        #pragma unroll
        for (int o = 32; o > 0; o >>= 1) acc += __shfl_xor(acc, o);
        if (j < NH) sm = fmaxf(sm, acc + ab[j]);
        else if (lane == 0) logits[(size_t)bl*NC + (j-NH)] = acc;
    }
    if (lane == 0) smax[bl] = sm;
}

// ---------------- K9b: per-b softmax over L + weighted logit sum -----------
__global__ __launch_bounds__(256) void k_final(const float* __restrict__ smax,
        const float* __restrict__ logits, const float* __restrict__ xmark,
        float* __restrict__ out) {
    __shared__ float e[L_];
    __shared__ float red[256];
    int b = blockIdx.x;
    int tid = threadIdx.x;
    float mx = -1e30f;
    for (int l = tid; l < L_; l += 256) {
        float s = smax[(size_t)b*L_ + l];
        e[l] = s;
        mx = fmaxf(mx, s);
    }
    #pragma unroll
    for (int o = 32; o > 0; o >>= 1) mx = fmaxf(mx, __shfl_xor(mx, o));
    red[tid] = mx;
    __syncthreads();
    mx = fmaxf(fmaxf(red[0], red[64]), fmaxf(red[128], red[192]));
    __syncthreads();
    float ssum = 0.f;
    for (int l = tid; l < L_; l += 256) {
        float ev = __expf(e[l] - mx);
        e[l] = ev;
        ssum += ev;
    }
    #pragma unroll
    for (int o = 32; o > 0; o >>= 1) ssum += __shfl_xor(ssum, o);
    if ((tid & 63) == 0) red[tid >> 6] = ssum;
    __syncthreads();
    float inv = 1.0f / (red[0]+red[1]+red[2]+red[3]);
    float acc[NC];
    #pragma unroll
    for (int c = 0; c < NC; ++c) acc[c] = 0.f;
    for (int l = tid; l < L_; l += 256) {
        float wl = e[l] * xmark[(size_t)b*L_ + l];
        const float* lg = logits + ((size_t)b*L_ + l)*NC;
        #pragma unroll
        for (int c = 0; c < NC; ++c) acc[c] = fmaf(wl, lg[c], acc[c]);
    }
    __syncthreads();
    for (int c = 0; c < NC; ++c) {
        red[tid] = acc[c];
        __syncthreads();
        if (tid < 64) {
            float s2 = red[tid]+red[tid+64]+red[tid+128]+red[tid+192];
            #pragma unroll
            for (int o = 32; o > 0; o >>= 1) s2 += __shfl_xor(s2, o);
            if (tid == 0) out[(size_t)b*NC + c] = s2 * inv;
        }
        __syncthreads();
    }
}

extern "C" void kernel_launch(void* const* d_in, const int* in_sizes, int n_in,
                              void* d_out, int out_size, void* d_ws, size_t ws_size,
                              hipStream_t stream) {
    const float* x_enc  = (const float*)d_in[0];
    const float* x_mark = (const float*)d_in[1];
    const float* cemb_w = (const float*)d_in[2];
    const float* inp_w  = (const float*)d_in[3];
    const float* c1_w   = (const float*)d_in[4];
    const float* c1_b   = (const float*)d_in[5];
    const float* xp_w   = (const float*)d_in[6];
    const float* dtp_w  = (const float*)d_in[7];
    const float* dtp_b  = (const float*)d_in[8];
    const float* A_log  = (const float*)d_in[9];
    const float* Dp     = (const float*)d_in[10];
    const float* outp_w = (const float*)d_in[11];
    const float* ln_g   = (const float*)d_in[12];
    const float* ln_b   = (const float*)d_in[13];
    const float* out_w  = (const float*)d_in[14];
    const float* attn_w = (const float*)d_in[15];
    const float* attn_b = (const float*)d_in[16];
    float* out = (float*)d_out;

    float* ws = (float*)d_ws;
    size_t o = 0;
    float* x    = ws + o; o += (size_t)M_TOT*DM;   // 33.5 MB
    float* xin  = ws + o; o += (size_t)M_TOT*DI;   // 67 MB
    float* z    = ws + o; o += (size_t)M_TOT*DI;   // 67 MB
    float* xc   = ws + o; o += (size_t)M_TOT*DI;   // 67 MB
    float* dbl  = ws + o; o += (size_t)M_TOT*48;   // 6.3 MB
    float* smax = ws + o; o += (size_t)M_TOT;      // 0.13 MB
    float* lgt  = ws + o; o += (size_t)M_TOT*NC;   // 1.3 MB
    float* dt = xin;   // xin dead after k_conv
    float* m  = x;     // x dead after in_proj GEMM

    k_embed <<<M_TOT, 256, 0, stream>>>(x_enc, cemb_w, x);
    k_gemm_nt<<<dim3(1024/BN, M_TOT/BM), 256, 0, stream>>>(x, inp_w, xin, z,
                                                           M_TOT, 1024, DM, DI);
    k_conv  <<<(M_TOT*DI)/256, 256, 0, stream>>>(xin, c1_w, c1_b, xc);
    k_xproj <<<M_TOT/8, 384, 0, stream>>>(xc, xp_w, dbl);
    k_dtproj<<<M_TOT/32, 256, 0, stream>>>(dbl, dtp_w, dtp_b, dt);
    k_scan  <<<B_*2, 256, 0, stream>>>(dt, xc, dbl, A_log, Dp, z);
    k_gemm_nt<<<dim3(DM/BN, M_TOT/BM), 256, 0, stream>>>(z, outp_w, m, m,
                                                         M_TOT, DM, DI, DM);
    k_ln    <<<M_TOT, 256, 0, stream>>>(m, ln_g, ln_b);
    k_heads <<<M_TOT, 64, 0, stream>>>(m, attn_w, attn_b, out_w, smax, lgt);
    k_final <<<B_, 256, 0, stream>>>(smax, lgt, x_mark, out);
}

// Round 4
// 1261.867 us; speedup vs baseline: 1.3132x; 1.3132x over previous
//
#include <hip/hip_runtime.h>
#include <hip/hip_bf16.h>
#include <math.h>

#define B_  32
#define L_  1024
#define CIN 3
#define DM  256
#define DI  512
#define NST 16
#define NH  8
#define NC  10
#define M_TOT (B_*L_)

static __device__ __forceinline__ float sigmoidf_(float x) {
    return 1.0f / (1.0f + __expf(-x));
}

// ---------------- K1: conv embedding + positional encoding ----------------
__global__ __launch_bounds__(256) void k_embed(const float* __restrict__ xe,
        const float* __restrict__ w, float* __restrict__ x) {
    int bl = blockIdx.x;
    int l = bl & (L_-1);
    int b = bl >> 10;
    int d = threadIdx.x;
    const float* xb = xe + (size_t)b * L_ * CIN;
    int t0 = l > 0 ? l-1 : 0;
    int t2 = l < L_-1 ? l+1 : L_-1;
    const float* w3 = w + d*9;
    float acc = 0.f;
    #pragma unroll
    for (int i = 0; i < 3; ++i) {
        acc += xb[t0*3+i] * w3[i*3+0];
        acc += xb[l *3+i] * w3[i*3+1];
        acc += xb[t2*3+i] * w3[i*3+2];
    }
    int j = d >> 1;
    float div = expf((float)(2*j) * (-logf(10000.0f)/(float)DM));
    float ang = (float)l * div;
    acc += (d & 1) ? cosf(ang) : sinf(ang);
    x[(size_t)bl*DM + d] = acc;
}

// ---------------- K2/K7: generic fp32 NT GEMM  C[m,n] = sum_k A[m,k]*W[n,k]
#define BM 128
#define BN 128
#define BK 8
__global__ __launch_bounds__(256) void k_gemm_nt(
        const float* __restrict__ A, const float* __restrict__ W,
        float* __restrict__ O1, float* __restrict__ O2,
        int M, int N, int K, int S) {
    __shared__ float As[BK][BM];
    __shared__ float Ws[BK][BN];
    int tid = threadIdx.x;
    int bx = blockIdx.x, by = blockIdx.y;
    int tx = tid & 15, ty = tid >> 4;
    int row0 = by*BM, col0 = bx*BN;
    int lr = tid >> 1;
    int lc = (tid & 1) * 4;
    const float* Ag = A + (size_t)(row0 + lr) * K + lc;
    const float* Wg = W + (size_t)(col0 + lr) * K + lc;
    float acc[8][8];
    #pragma unroll
    for (int i = 0; i < 8; ++i)
        #pragma unroll
        for (int j = 0; j < 8; ++j) acc[i][j] = 0.f;

    for (int k0 = 0; k0 < K; k0 += BK) {
        float4 av = *(const float4*)(Ag + k0);
        float4 wv = *(const float4*)(Wg + k0);
        __syncthreads();
        As[lc+0][lr] = av.x; As[lc+1][lr] = av.y; As[lc+2][lr] = av.z; As[lc+3][lr] = av.w;
        Ws[lc+0][lr] = wv.x; Ws[lc+1][lr] = wv.y; Ws[lc+2][lr] = wv.z; Ws[lc+3][lr] = wv.w;
        __syncthreads();
        #pragma unroll
        for (int k = 0; k < BK; ++k) {
            float4 a0 = *(const float4*)&As[k][ty*8];
            float4 a1 = *(const float4*)&As[k][ty*8+4];
            float4 b0 = *(const float4*)&Ws[k][tx*8];
            float4 b1 = *(const float4*)&Ws[k][tx*8+4];
            float ar[8] = {a0.x,a0.y,a0.z,a0.w,a1.x,a1.y,a1.z,a1.w};
            float br[8] = {b0.x,b0.y,b0.z,b0.w,b1.x,b1.y,b1.z,b1.w};
            #pragma unroll
            for (int i = 0; i < 8; ++i)
                #pragma unroll
                for (int j = 0; j < 8; ++j)
                    acc[i][j] = fmaf(ar[i], br[j], acc[i][j]);
        }
    }
    #pragma unroll
    for (int i = 0; i < 8; ++i) {
        size_t m = row0 + ty*8 + i;
        #pragma unroll
        for (int j = 0; j < 8; j += 4) {
            int n = col0 + tx*8 + j;
            float4 v = make_float4(acc[i][j],acc[i][j+1],acc[i][j+2],acc[i][j+3]);
            if (n < S) *(float4*)(O1 + m*(size_t)S + n) = v;
            else       *(float4*)(O2 + m*(size_t)(N-S) + (n-S)) = v;
        }
    }
}

// ---------------- K3: depthwise causal conv1d (k=4) + bias + silu ----------
__global__ __launch_bounds__(256) void k_conv(const float* __restrict__ xin,
        const float* __restrict__ w, const float* __restrict__ bias,
        float* __restrict__ xc) {
    size_t idx = (size_t)blockIdx.x * 256 + threadIdx.x;
    int d = (int)(idx & (DI-1));
    size_t m = idx >> 9;
    int l = (int)(m & (L_-1));
    float acc = bias[d];
    #pragma unroll
    for (int k = 0; k < 4; ++k) {
        int t = l + k - 3;
        if (t >= 0)
            acc = fmaf(xin[idx + ((size_t)(k-3))*DI], w[d*4 + k], acc);
    }
    xc[idx] = acc * sigmoidf_(acc);
}

// ---------------- K4: x_proj  dbl[m,e] = sum_d xc[m,d]*wp[e,d], e<48 -------
__global__ __launch_bounds__(384) void k_xproj(const float* __restrict__ xc,
        const float* __restrict__ wp, float* __restrict__ dbl) {
    __shared__ float ld[8][DI];
    size_t m0 = (size_t)blockIdx.x * 8;
    for (int idx = threadIdx.x; idx < 8*DI; idx += 384)
        ld[idx >> 9][idx & (DI-1)] = xc[m0*DI + idx];
    __syncthreads();
    int t = threadIdx.x;
    int r = t / 48, e = t % 48;
    const float4* a  = (const float4*)&ld[r][0];
    const float4* wv = (const float4*)(wp + (size_t)e*DI);
    float acc = 0.f;
    #pragma unroll 4
    for (int d4 = 0; d4 < DI/4; ++d4) {
        float4 av = a[d4], bv = wv[d4];
        acc += av.x*bv.x + av.y*bv.y + av.z*bv.z + av.w*bv.w;
    }
    dbl[(m0 + r)*48 + e] = acc;
}

// ---------------- K5: dt_proj (K=16) + softplus ----------------------------
__global__ __launch_bounds__(256) void k_dtproj(const float* __restrict__ dbl,
        const float* __restrict__ dtw, const float* __restrict__ dtb,
        float* __restrict__ dt) {
    __shared__ float wl[DI][17];
    __shared__ float rl[32][16];
    size_t m0 = (size_t)blockIdx.x * 32;
    for (int i = threadIdx.x; i < DI*16; i += 256)
        wl[i >> 4][i & 15] = dtw[i];
    for (int i = threadIdx.x; i < 32*16; i += 256)
        rl[i >> 4][i & 15] = dbl[(m0 + (i>>4))*48 + (i & 15)];
    __syncthreads();
    float b0 = dtb[threadIdx.x];
    float b1 = dtb[256 + threadIdx.x];
    for (int mm = 0; mm < 32; ++mm) {
        #pragma unroll
        for (int half = 0; half < 2; ++half) {
            int d = half*256 + threadIdx.x;
            float acc = half ? b1 : b0;
            #pragma unroll
            for (int r = 0; r < 16; ++r)
                acc = fmaf(rl[mm][r], wl[d][r], acc);
            float sp = fmaxf(acc, 0.f) + log1pf(__expf(-fabsf(acc)));
            dt[(m0+mm)*DI + d] = sp;
        }
    }
}

// ---------------- K6: selective scan v3 — state-parallel, shfl reduce ------
// 16 lanes per channel (one per state). Block = 256 thr = 16 channels.
// Grid = (DI/16, B_) = 1024 blocks. Out-of-place: reads z (gate), writes yb.
// No partial-object LDS writes; no DPP (only __shfl_xor).
#define SCAN_T 64
__global__ __launch_bounds__(256) void k_scan(const float* __restrict__ dt,
        const float* __restrict__ xc, const float* __restrict__ dbl,
        const float* __restrict__ A_log, const float* __restrict__ Dp,
        const float* __restrict__ z, float* __restrict__ yb) {
    __shared__ float4 sq4[SCAN_T*17];     // [t][ch]: dt, dt*x, x*D*gate, gate
    __shared__ float2 sBC2[SCAN_T*17];    // [t][n]: B(t), C(t)
    __shared__ float2 syT[16*33];         // [ch][t2]: y(2t2), y(2t2+1)

    int tid = threadIdx.x;
    int ch = tid >> 4;              // channel within block
    int n  = tid & 15;              // state index
    int d0 = blockIdx.x * 16;
    int b  = blockIdx.y;
    int d  = d0 + ch;
    float Avl2 = -expf(A_log[(size_t)d*NST + n]) * 1.44269504f;
    float h = 0.f;
    size_t base = (size_t)b * L_;

    // staging mapping: thread covers (t=st, channels/states sc..sc+3)
    int st = tid >> 2;
    int sc = (tid & 3) * 4;
    float4 Dv = *(const float4*)(Dp + d0 + sc);

    for (int t0 = 0; t0 < L_; t0 += SCAN_T) {
        __syncthreads();   // (A) prev writeout done before LDS overwrite
        {
            size_t row = base + t0 + st;
            float4 dtv = *(const float4*)(dt + row*DI + d0 + sc);
            float4 xv  = *(const float4*)(xc + row*DI + d0 + sc);
            float4 zv  = *(const float4*)(z  + row*DI + d0 + sc);
            float4 Bv  = *(const float4*)(dbl + row*48 + 16 + sc);
            float4 Cv  = *(const float4*)(dbl + row*48 + 32 + sc);
            float g0 = zv.x * sigmoidf_(zv.x);
            float g1 = zv.y * sigmoidf_(zv.y);
            float g2 = zv.z * sigmoidf_(zv.z);
            float g3 = zv.w * sigmoidf_(zv.w);
            sq4[st*17 + sc+0] = make_float4(dtv.x, dtv.x*xv.x, xv.x*Dv.x*g0, g0);
            sq4[st*17 + sc+1] = make_float4(dtv.y, dtv.y*xv.y, xv.y*Dv.y*g1, g1);
            sq4[st*17 + sc+2] = make_float4(dtv.z, dtv.z*xv.z, xv.z*Dv.z*g2, g2);
            sq4[st*17 + sc+3] = make_float4(dtv.w, dtv.w*xv.w, xv.w*Dv.w*g3, g3);
            sBC2[st*17 + sc+0] = make_float2(Bv.x, Cv.x);
            sBC2[st*17 + sc+1] = make_float2(Bv.y, Cv.y);
            sBC2[st*17 + sc+2] = make_float2(Bv.z, Cv.z);
            sBC2[st*17 + sc+3] = make_float2(Bv.w, Cv.w);
        }
        __syncthreads();   // (B)

        #pragma unroll 4
        for (int t2 = 0; t2 < SCAN_T/2; ++t2) {
            float2 bc0 = sBC2[(2*t2)*17 + n];
            float2 bc1 = sBC2[(2*t2+1)*17 + n];
            float4 q0 = sq4[(2*t2)*17 + ch];
            float4 q1 = sq4[(2*t2+1)*17 + ch];
            // even step
            float dA = exp2f(q0.x * Avl2);
            h = fmaf(dA, h, q0.y * bc0.x);
            float p0 = h * bc0.y;
            p0 += __shfl_xor(p0, 1);
            p0 += __shfl_xor(p0, 2);
            p0 += __shfl_xor(p0, 4);
            p0 += __shfl_xor(p0, 8);
            float y0 = fmaf(p0, q0.w, q0.z);
            // odd step
            dA = exp2f(q1.x * Avl2);
            h = fmaf(dA, h, q1.y * bc1.x);
            float p1 = h * bc1.y;
            p1 += __shfl_xor(p1, 1);
            p1 += __shfl_xor(p1, 2);
            p1 += __shfl_xor(p1, 4);
            p1 += __shfl_xor(p1, 8);
            float y1 = fmaf(p1, q1.w, q1.z);
            if (n == 0) syT[ch*33 + t2] = make_float2(y0, y1);
        }
        __syncthreads();   // (C)

        // cooperative vectorized writeout: thread (st, sc) -> row st, cols sc..sc+3
        {
            const float* syf = (const float*)syT;
            size_t row = base + t0 + st;
            int half = st & 1, t2i = st >> 1;
            float v0 = syf[((sc+0)*33 + t2i)*2 + half];
            float v1 = syf[((sc+1)*33 + t2i)*2 + half];
            float v2 = syf[((sc+2)*33 + t2i)*2 + half];
            float v3 = syf[((sc+3)*33 + t2i)*2 + half];
            *(float4*)(yb + row*DI + d0 + sc) = make_float4(v0,v1,v2,v3);
        }
    }
}

// ---------------- K8: LayerNorm + silu (in place) --------------------------
__global__ __launch_bounds__(256) void k_ln(float* __restrict__ m,
        const float* __restrict__ g, const float* __restrict__ bta) {
    __shared__ float sm[4];
    size_t row = blockIdx.x;
    int tid = threadIdx.x;
    float v = m[row*DM + tid];
    float s = v;
    #pragma unroll
    for (int o = 32; o > 0; o >>= 1) s += __shfl_xor(s, o);
    if ((tid & 63) == 0) sm[tid >> 6] = s;
    __syncthreads();
    float mu = (sm[0]+sm[1]+sm[2]+sm[3]) * (1.0f/DM);
    __syncthreads();
    float c = v - mu;
    float s2 = c*c;
    #pragma unroll
    for (int o = 32; o > 0; o >>= 1) s2 += __shfl_xor(s2, o);
    if ((tid & 63) == 0) sm[tid >> 6] = s2;
    __syncthreads();
    float var = (sm[0]+sm[1]+sm[2]+sm[3]) * (1.0f/DM);
    float o = c * (1.0f/sqrtf(var + 1e-5f)) * g[tid] + bta[tid];
    m[row*DM + tid] = o * sigmoidf_(o);
}

// ---------------- K9a: per-(b,l) attn-max + class logits -------------------
__global__ __launch_bounds__(64) void k_heads(const float* __restrict__ m,
        const float* __restrict__ aw, const float* __restrict__ ab,
        const float* __restrict__ ow, float* __restrict__ smax,
        float* __restrict__ logits) {
    int bl = blockIdx.x;
    int lane = threadIdx.x;
    const float* mr = m + (size_t)bl*DM;
    float v0 = mr[lane], v1 = mr[lane+64], v2 = mr[lane+128], v3 = mr[lane+192];
    float sm = -1e30f;
    for (int j = 0; j < NH+NC; ++j) {
        const float* wr = (j < NH) ? (aw + j*DM) : (ow + (j-NH)*DM);
        float acc = v0*wr[lane] + v1*wr[lane+64] + v2*wr[lane+128] + v3*wr[lane+192];
        #pragma unroll
        for (int o = 32; o > 0; o >>= 1) acc += __shfl_xor(acc, o);
        if (j < NH) sm = fmaxf(sm, acc + ab[j]);
        else if (lane == 0) logits[(size_t)bl*NC + (j-NH)] = acc;
    }
    if (lane == 0) smax[bl] = sm;
}

// ---------------- K9b: per-b softmax over L + weighted logit sum -----------
__global__ __launch_bounds__(256) void k_final(const float* __restrict__ smax,
        const float* __restrict__ logits, const float* __restrict__ xmark,
        float* __restrict__ out) {
    __shared__ float e[L_];
    __shared__ float red[256];
    int b = blockIdx.x;
    int tid = threadIdx.x;
    float mx = -1e30f;
    for (int l = tid; l < L_; l += 256) {
        float s = smax[(size_t)b*L_ + l];
        e[l] = s;
        mx = fmaxf(mx, s);
    }
    #pragma unroll
    for (int o = 32; o > 0; o >>= 1) mx = fmaxf(mx, __shfl_xor(mx, o));
    red[tid] = mx;
    __syncthreads();
    mx = fmaxf(fmaxf(red[0], red[64]), fmaxf(red[128], red[192]));
    __syncthreads();
    float ssum = 0.f;
    for (int l = tid; l < L_; l += 256) {
        float ev = __expf(e[l] - mx);
        e[l] = ev;
        ssum += ev;
    }
    #pragma unroll
    for (int o = 32; o > 0; o >>= 1) ssum += __shfl_xor(ssum, o);
    if ((tid & 63) == 0) red[tid >> 6] = ssum;
    __syncthreads();
    float inv = 1.0f / (red[0]+red[1]+red[2]+red[3]);
    float acc[NC];
    #pragma unroll
    for (int c = 0; c < NC; ++c) acc[c] = 0.f;
    for (int l = tid; l < L_; l += 256) {
        float wl = e[l] * xmark[(size_t)b*L_ + l];
        const float* lg = logits + ((size_t)b*L_ + l)*NC;
        #pragma unroll
        for (int c = 0; c < NC; ++c) acc[c] = fmaf(wl, lg[c], acc[c]);
    }
    __syncthreads();
    for (int c = 0; c < NC; ++c) {
        red[tid] = acc[c];
        __syncthreads();
        if (tid < 64) {
            float s2 = red[tid]+red[tid+64]+red[tid+128]+red[tid+192];
            #pragma unroll
            for (int o = 32; o > 0; o >>= 1) s2 += __shfl_xor(s2, o);
            if (tid == 0) out[(size_t)b*NC + c] = s2 * inv;
        }
        __syncthreads();
    }
}

extern "C" void kernel_launch(void* const* d_in, const int* in_sizes, int n_in,
                              void* d_out, int out_size, void* d_ws, size_t ws_size,
                              hipStream_t stream) {
    const float* x_enc  = (const float*)d_in[0];
    const float* x_mark = (const float*)d_in[1];
    const float* cemb_w = (const float*)d_in[2];
    const float* inp_w  = (const float*)d_in[3];
    const float* c1_w   = (const float*)d_in[4];
    const float* c1_b   = (const float*)d_in[5];
    const float* xp_w   = (const float*)d_in[6];
    const float* dtp_w  = (const float*)d_in[7];
    const float* dtp_b  = (const float*)d_in[8];
    const float* A_log  = (const float*)d_in[9];
    const float* Dp     = (const float*)d_in[10];
    const float* outp_w = (const float*)d_in[11];
    const float* ln_g   = (const float*)d_in[12];
    const float* ln_b   = (const float*)d_in[13];
    const float* out_w  = (const float*)d_in[14];
    const float* attn_w = (const float*)d_in[15];
    const float* attn_b = (const float*)d_in[16];
    float* out = (float*)d_out;

    float* ws = (float*)d_ws;
    size_t o = 0;
    float* x    = ws + o; o += (size_t)M_TOT*DM;
    float* xin  = ws + o; o += (size_t)M_TOT*DI;
    float* z    = ws + o; o += (size_t)M_TOT*DI;
    float* xc   = ws + o; o += (size_t)M_TOT*DI;
    float* dbl  = ws + o; o += (size_t)M_TOT*48;
    float* smax = ws + o; o += (size_t)M_TOT;
    float* lgt  = ws + o; o += (size_t)M_TOT*NC;
    float* dt = xin;   // xin dead after k_conv
    float* yb = x;     // x dead after in_proj GEMM; scan output (y)
    float* mm = xc;    // xc dead after k_scan; out_proj output (m)

    k_embed <<<M_TOT, 256, 0, stream>>>(x_enc, cemb_w, x);
    k_gemm_nt<<<dim3(1024/BN, M_TOT/BM), 256, 0, stream>>>(x, inp_w, xin, z,
                                                           M_TOT, 1024, DM, DI);
    k_conv  <<<(M_TOT*DI)/256, 256, 0, stream>>>(xin, c1_w, c1_b, xc);
    k_xproj <<<M_TOT/8, 384, 0, stream>>>(xc, xp_w, dbl);
    k_dtproj<<<M_TOT/32, 256, 0, stream>>>(dbl, dtp_w, dtp_b, dt);
    k_scan  <<<dim3(DI/16, B_), 256, 0, stream>>>(dt, xc, dbl, A_log, Dp, z, yb);
    k_gemm_nt<<<dim3(DM/BN, M_TOT/BM), 256, 0, stream>>>(yb, outp_w, mm, mm,
                                                         M_TOT, DM, DI, DM);
    k_ln    <<<M_TOT, 256, 0, stream>>>(mm, ln_g, ln_b);
    k_heads <<<M_TOT, 64, 0, stream>>>(mm, attn_w, attn_b, out_w, smax, lgt);
    k_final <<<B_, 256, 0, stream>>>(smax, lgt, x_mark, out);
}

// Round 7
// 1064.343 us; speedup vs baseline: 1.5569x; 1.1856x over previous
//
#include <hip/hip_runtime.h>
#include <hip/hip_bf16.h>
#include <math.h>

#define B_  32
#define L_  1024
#define CIN 3
#define DM  256
#define DI  512
#define NST 16
#define NH  8
#define NC  10
#define M_TOT (B_*L_)

static __device__ __forceinline__ float sigmoidf_(float x) {
    return 1.0f / (1.0f + __expf(-x));
}

// ---------------- K1: conv embedding + positional encoding ----------------
__global__ __launch_bounds__(256) void k_embed(const float* __restrict__ xe,
        const float* __restrict__ w, float* __restrict__ x) {
    int bl = blockIdx.x;
    int l = bl & (L_-1);
    int b = bl >> 10;
    int d = threadIdx.x;
    const float* xb = xe + (size_t)b * L_ * CIN;
    int t0 = l > 0 ? l-1 : 0;
    int t2 = l < L_-1 ? l+1 : L_-1;
    const float* w3 = w + d*9;
    float acc = 0.f;
    #pragma unroll
    for (int i = 0; i < 3; ++i) {
        acc += xb[t0*3+i] * w3[i*3+0];
        acc += xb[l *3+i] * w3[i*3+1];
        acc += xb[t2*3+i] * w3[i*3+2];
    }
    int j = d >> 1;
    float div = expf((float)(2*j) * (-logf(10000.0f)/(float)DM));
    float ang = (float)l * div;
    acc += (d & 1) ? cosf(ang) : sinf(ang);
    x[(size_t)bl*DM + d] = acc;
}

// ---------------- K2/K7: generic fp32 NT GEMM  C[m,n] = sum_k A[m,k]*W[n,k]
#define BM 128
#define BN 128
#define BK 8
__global__ __launch_bounds__(256) void k_gemm_nt(
        const float* __restrict__ A, const float* __restrict__ W,
        float* __restrict__ O1, float* __restrict__ O2,
        int M, int N, int K, int S) {
    __shared__ float As[BK][BM];
    __shared__ float Ws[BK][BN];
    int tid = threadIdx.x;
    int bx = blockIdx.x, by = blockIdx.y;
    int tx = tid & 15, ty = tid >> 4;
    int row0 = by*BM, col0 = bx*BN;
    int lr = tid >> 1;
    int lc = (tid & 1) * 4;
    const float* Ag = A + (size_t)(row0 + lr) * K + lc;
    const float* Wg = W + (size_t)(col0 + lr) * K + lc;
    float acc[8][8];
    #pragma unroll
    for (int i = 0; i < 8; ++i)
        #pragma unroll
        for (int j = 0; j < 8; ++j) acc[i][j] = 0.f;

    for (int k0 = 0; k0 < K; k0 += BK) {
        float4 av = *(const float4*)(Ag + k0);
        float4 wv = *(const float4*)(Wg + k0);
        __syncthreads();
        As[lc+0][lr] = av.x; As[lc+1][lr] = av.y; As[lc+2][lr] = av.z; As[lc+3][lr] = av.w;
        Ws[lc+0][lr] = wv.x; Ws[lc+1][lr] = wv.y; Ws[lc+2][lr] = wv.z; Ws[lc+3][lr] = wv.w;
        __syncthreads();
        #pragma unroll
        for (int k = 0; k < BK; ++k) {
            float4 a0 = *(const float4*)&As[k][ty*8];
            float4 a1 = *(const float4*)&As[k][ty*8+4];
            float4 b0 = *(const float4*)&Ws[k][tx*8];
            float4 b1 = *(const float4*)&Ws[k][tx*8+4];
            float ar[8] = {a0.x,a0.y,a0.z,a0.w,a1.x,a1.y,a1.z,a1.w};
            float br[8] = {b0.x,b0.y,b0.z,b0.w,b1.x,b1.y,b1.z,b1.w};
            #pragma unroll
            for (int i = 0; i < 8; ++i)
                #pragma unroll
                for (int j = 0; j < 8; ++j)
                    acc[i][j] = fmaf(ar[i], br[j], acc[i][j]);
        }
    }
    #pragma unroll
    for (int i = 0; i < 8; ++i) {
        size_t m = row0 + ty*8 + i;
        #pragma unroll
        for (int j = 0; j < 8; j += 4) {
            int n = col0 + tx*8 + j;
            float4 v = make_float4(acc[i][j],acc[i][j+1],acc[i][j+2],acc[i][j+3]);
            if (n < S) *(float4*)(O1 + m*(size_t)S + n) = v;
            else       *(float4*)(O2 + m*(size_t)(N-S) + (n-S)) = v;
        }
    }
}

// ---------------- K3: depthwise causal conv1d (k=4) + bias + silu ----------
__global__ __launch_bounds__(256) void k_conv(const float* __restrict__ xin,
        const float* __restrict__ w, const float* __restrict__ bias,
        float* __restrict__ xc) {
    size_t idx = (size_t)blockIdx.x * 256 + threadIdx.x;
    int d = (int)(idx & (DI-1));
    size_t m = idx >> 9;
    int l = (int)(m & (L_-1));
    float acc = bias[d];
    #pragma unroll
    for (int k = 0; k < 4; ++k) {
        int t = l + k - 3;
        if (t >= 0)
            acc = fmaf(xin[idx + ((size_t)(k-3))*DI], w[d*4 + k], acc);
    }
    xc[idx] = acc * sigmoidf_(acc);
}

// ---------------- K4: x_proj v2 — tiled fp32 GEMM, M x 48, K=512 ----------
// BM=128 rows/block, BK=16. 256 thr: tx(16) -> 3 cols, ty(16) -> 8 rows.
// Conflict-free: As read = 4-addr broadcast; Ws read addrs distinct mod 32.
#define XBM 128
#define XBK 16
__global__ __launch_bounds__(256) void k_xproj(const float* __restrict__ xc,
        const float* __restrict__ wp, float* __restrict__ dbl) {
    __shared__ float As[XBK][XBM];   // 8 KB
    __shared__ float Ws[XBK][48];    // 3 KB
    int tid = threadIdx.x;
    int row0 = blockIdx.x * XBM;
    int lr = tid >> 1;              // 0..127 (staging row)
    int lk = (tid & 1) * 8;         // 0 or 8 (staging k-offset)
    int we = tid >> 2;              // 0..47 (staging e, tid<192)
    int wk = (tid & 3) * 4;         // staging k-offset for W
    int tx = tid & 15;              // cols tx*3 .. tx*3+2
    int ty = tid >> 4;              // rows ty*8 .. ty*8+7
    float acc[8][3];
    #pragma unroll
    for (int i = 0; i < 8; ++i)
        #pragma unroll
        for (int j = 0; j < 3; ++j) acc[i][j] = 0.f;

    for (int k0 = 0; k0 < DI; k0 += XBK) {
        float4 a0 = *(const float4*)(xc + (size_t)(row0+lr)*DI + k0 + lk);
        float4 a1 = *(const float4*)(xc + (size_t)(row0+lr)*DI + k0 + lk + 4);
        float4 w0 = make_float4(0.f,0.f,0.f,0.f);
        if (tid < 192) w0 = *(const float4*)(wp + (size_t)we*DI + k0 + wk);
        __syncthreads();
        As[lk+0][lr]=a0.x; As[lk+1][lr]=a0.y; As[lk+2][lr]=a0.z; As[lk+3][lr]=a0.w;
        As[lk+4][lr]=a1.x; As[lk+5][lr]=a1.y; As[lk+6][lr]=a1.z; As[lk+7][lr]=a1.w;
        if (tid < 192) {
            Ws[wk+0][we]=w0.x; Ws[wk+1][we]=w0.y; Ws[wk+2][we]=w0.z; Ws[wk+3][we]=w0.w;
        }
        __syncthreads();
        #pragma unroll
        for (int k = 0; k < XBK; ++k) {
            float4 av0 = *(const float4*)&As[k][ty*8];
            float4 av1 = *(const float4*)&As[k][ty*8+4];
            float w0_ = Ws[k][tx*3+0];
            float w1_ = Ws[k][tx*3+1];
            float w2_ = Ws[k][tx*3+2];
            float ar[8] = {av0.x,av0.y,av0.z,av0.w,av1.x,av1.y,av1.z,av1.w};
            #pragma unroll
            for (int i = 0; i < 8; ++i) {
                acc[i][0] = fmaf(ar[i], w0_, acc[i][0]);
                acc[i][1] = fmaf(ar[i], w1_, acc[i][1]);
                acc[i][2] = fmaf(ar[i], w2_, acc[i][2]);
            }
        }
    }
    #pragma unroll
    for (int i = 0; i < 8; ++i) {
        size_t r = row0 + ty*8 + i;
        #pragma unroll
        for (int j = 0; j < 3; ++j)
            dbl[r*48 + tx*3 + j] = acc[i][j];
    }
}

// ---------------- K5: dt_proj (K=16) + softplus ----------------------------
__global__ __launch_bounds__(256) void k_dtproj(const float* __restrict__ dbl,
        const float* __restrict__ dtw, const float* __restrict__ dtb,
        float* __restrict__ dt) {
    __shared__ float wl[DI][17];
    __shared__ float rl[32][16];
    size_t m0 = (size_t)blockIdx.x * 32;
    for (int i = threadIdx.x; i < DI*16; i += 256)
        wl[i >> 4][i & 15] = dtw[i];
    for (int i = threadIdx.x; i < 32*16; i += 256)
        rl[i >> 4][i & 15] = dbl[(m0 + (i>>4))*48 + (i & 15)];
    __syncthreads();
    float b0 = dtb[threadIdx.x];
    float b1 = dtb[256 + threadIdx.x];
    for (int mm = 0; mm < 32; ++mm) {
        #pragma unroll
        for (int half = 0; half < 2; ++half) {
            int d = half*256 + threadIdx.x;
            float acc = half ? b1 : b0;
            #pragma unroll
            for (int r = 0; r < 16; ++r)
                acc = fmaf(rl[mm][r], wl[d][r], acc);
            float sp = fmaxf(acc, 0.f) + log1pf(__expf(-fabsf(acc)));
            dt[(m0+mm)*DI + d] = sp;
        }
    }
}

// ---------------- K6: selective scan v3 — state-parallel, shfl reduce ------
#define SCAN_T 64
__global__ __launch_bounds__(256) void k_scan(const float* __restrict__ dt,
        const float* __restrict__ xc, const float* __restrict__ dbl,
        const float* __restrict__ A_log, const float* __restrict__ Dp,
        const float* __restrict__ z, float* __restrict__ yb) {
    __shared__ float4 sq4[SCAN_T*17];     // [t][ch]: dt, dt*x, x*D*gate, gate
    __shared__ float2 sBC2[SCAN_T*17];    // [t][n]: B(t), C(t)
    __shared__ float2 syT[16*33];         // [ch][t2]: y(2t2), y(2t2+1)

    int tid = threadIdx.x;
    int ch = tid >> 4;              // channel within block
    int n  = tid & 15;              // state index
    int d0 = blockIdx.x * 16;
    int b  = blockIdx.y;
    int d  = d0 + ch;
    float Avl2 = -expf(A_log[(size_t)d*NST + n]) * 1.44269504f;
    float h = 0.f;
    size_t base = (size_t)b * L_;

    int st = tid >> 2;
    int sc = (tid & 3) * 4;
    float4 Dv = *(const float4*)(Dp + d0 + sc);

    for (int t0 = 0; t0 < L_; t0 += SCAN_T) {
        __syncthreads();   // (A) prev writeout done before LDS overwrite
        {
            size_t row = base + t0 + st;
            float4 dtv = *(const float4*)(dt + row*DI + d0 + sc);
            float4 xv  = *(const float4*)(xc + row*DI + d0 + sc);
            float4 zv  = *(const float4*)(z  + row*DI + d0 + sc);
            float4 Bv  = *(const float4*)(dbl + row*48 + 16 + sc);
            float4 Cv  = *(const float4*)(dbl + row*48 + 32 + sc);
            float g0 = zv.x * sigmoidf_(zv.x);
            float g1 = zv.y * sigmoidf_(zv.y);
            float g2 = zv.z * sigmoidf_(zv.z);
            float g3 = zv.w * sigmoidf_(zv.w);
            sq4[st*17 + sc+0] = make_float4(dtv.x, dtv.x*xv.x, xv.x*Dv.x*g0, g0);
            sq4[st*17 + sc+1] = make_float4(dtv.y, dtv.y*xv.y, xv.y*Dv.y*g1, g1);
            sq4[st*17 + sc+2] = make_float4(dtv.z, dtv.z*xv.z, xv.z*Dv.z*g2, g2);
            sq4[st*17 + sc+3] = make_float4(dtv.w, dtv.w*xv.w, xv.w*Dv.w*g3, g3);
            sBC2[st*17 + sc+0] = make_float2(Bv.x, Cv.x);
            sBC2[st*17 + sc+1] = make_float2(Bv.y, Cv.y);
            sBC2[st*17 + sc+2] = make_float2(Bv.z, Cv.z);
            sBC2[st*17 + sc+3] = make_float2(Bv.w, Cv.w);
        }
        __syncthreads();   // (B)

        #pragma unroll 4
        for (int t2 = 0; t2 < SCAN_T/2; ++t2) {
            float2 bc0 = sBC2[(2*t2)*17 + n];
            float2 bc1 = sBC2[(2*t2+1)*17 + n];
            float4 q0 = sq4[(2*t2)*17 + ch];
            float4 q1 = sq4[(2*t2+1)*17 + ch];
            float dA = exp2f(q0.x * Avl2);
            h = fmaf(dA, h, q0.y * bc0.x);
            float p0 = h * bc0.y;
            p0 += __shfl_xor(p0, 1);
            p0 += __shfl_xor(p0, 2);
            p0 += __shfl_xor(p0, 4);
            p0 += __shfl_xor(p0, 8);
            float y0 = fmaf(p0, q0.w, q0.z);
            dA = exp2f(q1.x * Avl2);
            h = fmaf(dA, h, q1.y * bc1.x);
            float p1 = h * bc1.y;
            p1 += __shfl_xor(p1, 1);
            p1 += __shfl_xor(p1, 2);
            p1 += __shfl_xor(p1, 4);
            p1 += __shfl_xor(p1, 8);
            float y1 = fmaf(p1, q1.w, q1.z);
            if (n == 0) syT[ch*33 + t2] = make_float2(y0, y1);
        }
        __syncthreads();   // (C)

        {
            const float* syf = (const float*)syT;
            size_t row = base + t0 + st;
            int half = st & 1, t2i = st >> 1;
            float v0 = syf[((sc+0)*33 + t2i)*2 + half];
            float v1 = syf[((sc+1)*33 + t2i)*2 + half];
            float v2 = syf[((sc+2)*33 + t2i)*2 + half];
            float v3 = syf[((sc+3)*33 + t2i)*2 + half];
            *(float4*)(yb + row*DI + d0 + sc) = make_float4(v0,v1,v2,v3);
        }
    }
}

// ---------------- K8: fused LayerNorm + silu + attn-max + class logits -----
__global__ __launch_bounds__(256) void k_lnheads(const float* __restrict__ m,
        const float* __restrict__ g, const float* __restrict__ bta,
        const float* __restrict__ aw, const float* __restrict__ ab,
        const float* __restrict__ ow, float* __restrict__ smax,
        float* __restrict__ logits) {
    __shared__ float sm[4];
    __shared__ float red[18][4];
    __shared__ float fin[18];
    size_t row = blockIdx.x;
    int tid = threadIdx.x;
    int wv = tid >> 6;
    int lane = tid & 63;
    float v = m[row*DM + tid];
    // mean
    float s = v;
    #pragma unroll
    for (int o = 32; o > 0; o >>= 1) s += __shfl_xor(s, o);
    if (lane == 0) sm[wv] = s;
    __syncthreads();
    float mu = (sm[0]+sm[1]+sm[2]+sm[3]) * (1.0f/DM);
    __syncthreads();
    // var
    float c = v - mu;
    float s2 = c*c;
    #pragma unroll
    for (int o = 32; o > 0; o >>= 1) s2 += __shfl_xor(s2, o);
    if (lane == 0) sm[wv] = s2;
    __syncthreads();
    float var = (sm[0]+sm[1]+sm[2]+sm[3]) * (1.0f/DM);
    float o = c * (1.0f/sqrtf(var + 1e-5f)) * g[tid] + bta[tid];
    float ov = o * sigmoidf_(o);
    // 18 dot products (8 heads + 10 classes)
    #pragma unroll
    for (int j = 0; j < NH+NC; ++j) {
        const float* wr = (j < NH) ? (aw + j*DM) : (ow + (j-NH)*DM);
        float p = ov * wr[tid];
        #pragma unroll
        for (int off = 32; off > 0; off >>= 1) p += __shfl_xor(p, off);
        if (lane == 0) red[j][wv] = p;
    }
    __syncthreads();
    if (tid < 18)
        fin[tid] = red[tid][0]+red[tid][1]+red[tid][2]+red[tid][3];
    __syncthreads();
    if (tid == 0) {
        float mx = fin[0] + ab[0];
        #pragma unroll
        for (int j = 1; j < NH; ++j) mx = fmaxf(mx, fin[j] + ab[j]);
        smax[row] = mx;
    }
    if (tid >= 8 && tid < 18)
        logits[row*NC + (tid-8)] = fin[tid];
}

// ---------------- K9b: per-b softmax over L + weighted logit sum -----------
__global__ __launch_bounds__(256) void k_final(const float* __restrict__ smax,
        const float* __restrict__ logits, const float* __restrict__ xmark,
        float* __restrict__ out) {
    __shared__ float e[L_];
    __shared__ float red[256];
    int b = blockIdx.x;
    int tid = threadIdx.x;
    float mx = -1e30f;
    for (int l = tid; l < L_; l += 256) {
        float s = smax[(size_t)b*L_ + l];
        e[l] = s;
        mx = fmaxf(mx, s);
    }
    #pragma unroll
    for (int o = 32; o > 0; o >>= 1) mx = fmaxf(mx, __shfl_xor(mx, o));
    red[tid] = mx;
    __syncthreads();
    mx = fmaxf(fmaxf(red[0], red[64]), fmaxf(red[128], red[192]));
    __syncthreads();
    float ssum = 0.f;
    for (int l = tid; l < L_; l += 256) {
        float ev = __expf(e[l] - mx);
        e[l] = ev;
        ssum += ev;
    }
    #pragma unroll
    for (int o = 32; o > 0; o >>= 1) ssum += __shfl_xor(ssum, o);
    if ((tid & 63) == 0) red[tid >> 6] = ssum;
    __syncthreads();
    float inv = 1.0f / (red[0]+red[1]+red[2]+red[3]);
    float acc[NC];
    #pragma unroll
    for (int c = 0; c < NC; ++c) acc[c] = 0.f;
    for (int l = tid; l < L_; l += 256) {
        float wl = e[l] * xmark[(size_t)b*L_ + l];
        const float* lg = logits + ((size_t)b*L_ + l)*NC;
        #pragma unroll
        for (int c = 0; c < NC; ++c) acc[c] = fmaf(wl, lg[c], acc[c]);
    }
    __syncthreads();
    for (int c = 0; c < NC; ++c) {
        red[tid] = acc[c];
        __syncthreads();
        if (tid < 64) {
            float s2 = red[tid]+red[tid+64]+red[tid+128]+red[tid+192];
            #pragma unroll
            for (int o = 32; o > 0; o >>= 1) s2 += __shfl_xor(s2, o);
            if (tid == 0) out[(size_t)b*NC + c] = s2 * inv;
        }
        __syncthreads();
    }
}

extern "C" void kernel_launch(void* const* d_in, const int* in_sizes, int n_in,
                              void* d_out, int out_size, void* d_ws, size_t ws_size,
                              hipStream_t stream) {
    const float* x_enc  = (const float*)d_in[0];
    const float* x_mark = (const float*)d_in[1];
    const float* cemb_w = (const float*)d_in[2];
    const float* inp_w  = (const float*)d_in[3];
    const float* c1_w   = (const float*)d_in[4];
    const float* c1_b   = (const float*)d_in[5];
    const float* xp_w   = (const float*)d_in[6];
    const float* dtp_w  = (const float*)d_in[7];
    const float* dtp_b  = (const float*)d_in[8];
    const float* A_log  = (const float*)d_in[9];
    const float* Dp     = (const float*)d_in[10];
    const float* outp_w = (const float*)d_in[11];
    const float* ln_g   = (const float*)d_in[12];
    const float* ln_b   = (const float*)d_in[13];
    const float* out_w  = (const float*)d_in[14];
    const float* attn_w = (const float*)d_in[15];
    const float* attn_b = (const float*)d_in[16];
    float* out = (float*)d_out;

    float* ws = (float*)d_ws;
    size_t o = 0;
    float* x    = ws + o; o += (size_t)M_TOT*DM;
    float* xin  = ws + o; o += (size_t)M_TOT*DI;
    float* z    = ws + o; o += (size_t)M_TOT*DI;
    float* xc   = ws + o; o += (size_t)M_TOT*DI;
    float* dbl  = ws + o; o += (size_t)M_TOT*48;
    float* smax = ws + o; o += (size_t)M_TOT;
    float* lgt  = ws + o; o += (size_t)M_TOT*NC;
    float* dt = xin;   // xin dead after k_conv
    float* yb = x;     // x dead after in_proj GEMM; scan output (y)
    float* mm = xc;    // xc dead after k_scan; out_proj output (m)

    k_embed <<<M_TOT, 256, 0, stream>>>(x_enc, cemb_w, x);
    k_gemm_nt<<<dim3(1024/BN, M_TOT/BM), 256, 0, stream>>>(x, inp_w, xin, z,
                                                           M_TOT, 1024, DM, DI);
    k_conv  <<<(M_TOT*DI)/256, 256, 0, stream>>>(xin, c1_w, c1_b, xc);
    k_xproj <<<M_TOT/XBM, 256, 0, stream>>>(xc, xp_w, dbl);
    k_dtproj<<<M_TOT/32, 256, 0, stream>>>(dbl, dtp_w, dtp_b, dt);
    k_scan  <<<dim3(DI/16, B_), 256, 0, stream>>>(dt, xc, dbl, A_log, Dp, z, yb);
    k_gemm_nt<<<dim3(DM/BN, M_TOT/BM), 256, 0, stream>>>(yb, outp_w, mm, mm,
                                                         M_TOT, DM, DI, DM);
    k_lnheads<<<M_TOT, 256, 0, stream>>>(mm, ln_g, ln_b, attn_w, attn_b,
                                         out_w, smax, lgt);
    k_final <<<B_, 256, 0, stream>>>(smax, lgt, x_mark, out);
}

// Round 8
// 907.607 us; speedup vs baseline: 1.8257x; 1.1727x over previous
//
#include <hip/hip_runtime.h>
#include <hip/hip_bf16.h>
#include <math.h>

#define B_  32
#define L_  1024
#define CIN 3
#define DM  256
#define DI  512
#define NST 16
#define NH  8
#define NC  10
#define M_TOT (B_*L_)

static __device__ __forceinline__ float sigmoidf_(float x) {
    return 1.0f / (1.0f + __expf(-x));
}

// 16-lane sum via DPP (VALU pipe; DS pipe untouched). Both p0,p1 reduced,
// interleaved to fill hazard slots; s_nop 1 guards VALU->DPP waitstates.
// After this, EVERY lane of each 16-lane row holds the row total.
static __device__ __forceinline__ void reduce16_pair(float& a, float& b) {
    asm volatile(
        "s_nop 1\n\t"
        "v_add_f32 %0, %0, %0 quad_perm:[1,0,3,2] row_mask:0xf bank_mask:0xf\n\t"
        "v_add_f32 %1, %1, %1 quad_perm:[1,0,3,2] row_mask:0xf bank_mask:0xf\n\t"
        "s_nop 1\n\t"
        "v_add_f32 %0, %0, %0 quad_perm:[2,3,0,1] row_mask:0xf bank_mask:0xf\n\t"
        "v_add_f32 %1, %1, %1 quad_perm:[2,3,0,1] row_mask:0xf bank_mask:0xf\n\t"
        "s_nop 1\n\t"
        "v_add_f32 %0, %0, %0 row_ror:4 row_mask:0xf bank_mask:0xf\n\t"
        "v_add_f32 %1, %1, %1 row_ror:4 row_mask:0xf bank_mask:0xf\n\t"
        "s_nop 1\n\t"
        "v_add_f32 %0, %0, %0 row_ror:8 row_mask:0xf bank_mask:0xf\n\t"
        "v_add_f32 %1, %1, %1 row_ror:8 row_mask:0xf bank_mask:0xf\n\t"
        "s_nop 1\n\t"
        : "+v"(a), "+v"(b));
}

// ---------------- K1: conv embedding + positional encoding ----------------
__global__ __launch_bounds__(256) void k_embed(const float* __restrict__ xe,
        const float* __restrict__ w, float* __restrict__ x) {
    int bl = blockIdx.x;
    int l = bl & (L_-1);
    int b = bl >> 10;
    int d = threadIdx.x;
    const float* xb = xe + (size_t)b * L_ * CIN;
    int t0 = l > 0 ? l-1 : 0;
    int t2 = l < L_-1 ? l+1 : L_-1;
    const float* w3 = w + d*9;
    float acc = 0.f;
    #pragma unroll
    for (int i = 0; i < 3; ++i) {
        acc += xb[t0*3+i] * w3[i*3+0];
        acc += xb[l *3+i] * w3[i*3+1];
        acc += xb[t2*3+i] * w3[i*3+2];
    }
    int j = d >> 1;
    float div = expf((float)(2*j) * (-logf(10000.0f)/(float)DM));
    float ang = (float)l * div;
    acc += (d & 1) ? cosf(ang) : sinf(ang);
    x[(size_t)bl*DM + d] = acc;
}

// ---------------- K2/K7: generic fp32 NT GEMM  C[m,n] = sum_k A[m,k]*W[n,k]
#define BM 128
#define BN 128
#define BK 8
__global__ __launch_bounds__(256) void k_gemm_nt(
        const float* __restrict__ A, const float* __restrict__ W,
        float* __restrict__ O1, float* __restrict__ O2,
        int M, int N, int K, int S) {
    __shared__ float As[BK][BM];
    __shared__ float Ws[BK][BN];
    int tid = threadIdx.x;
    int bx = blockIdx.x, by = blockIdx.y;
    int tx = tid & 15, ty = tid >> 4;
    int row0 = by*BM, col0 = bx*BN;
    int lr = tid >> 1;
    int lc = (tid & 1) * 4;
    const float* Ag = A + (size_t)(row0 + lr) * K + lc;
    const float* Wg = W + (size_t)(col0 + lr) * K + lc;
    float acc[8][8];
    #pragma unroll
    for (int i = 0; i < 8; ++i)
        #pragma unroll
        for (int j = 0; j < 8; ++j) acc[i][j] = 0.f;

    for (int k0 = 0; k0 < K; k0 += BK) {
        float4 av = *(const float4*)(Ag + k0);
        float4 wv = *(const float4*)(Wg + k0);
        __syncthreads();
        As[lc+0][lr] = av.x; As[lc+1][lr] = av.y; As[lc+2][lr] = av.z; As[lc+3][lr] = av.w;
        Ws[lc+0][lr] = wv.x; Ws[lc+1][lr] = wv.y; Ws[lc+2][lr] = wv.z; Ws[lc+3][lr] = wv.w;
        __syncthreads();
        #pragma unroll
        for (int k = 0; k < BK; ++k) {
            float4 a0 = *(const float4*)&As[k][ty*8];
            float4 a1 = *(const float4*)&As[k][ty*8+4];
            float4 b0 = *(const float4*)&Ws[k][tx*8];
            float4 b1 = *(const float4*)&Ws[k][tx*8+4];
            float ar[8] = {a0.x,a0.y,a0.z,a0.w,a1.x,a1.y,a1.z,a1.w};
            float br[8] = {b0.x,b0.y,b0.z,b0.w,b1.x,b1.y,b1.z,b1.w};
            #pragma unroll
            for (int i = 0; i < 8; ++i)
                #pragma unroll
                for (int j = 0; j < 8; ++j)
                    acc[i][j] = fmaf(ar[i], br[j], acc[i][j]);
        }
    }
    #pragma unroll
    for (int i = 0; i < 8; ++i) {
        size_t m = row0 + ty*8 + i;
        #pragma unroll
        for (int j = 0; j < 8; j += 4) {
            int n = col0 + tx*8 + j;
            float4 v = make_float4(acc[i][j],acc[i][j+1],acc[i][j+2],acc[i][j+3]);
            if (n < S) *(float4*)(O1 + m*(size_t)S + n) = v;
            else       *(float4*)(O2 + m*(size_t)(N-S) + (n-S)) = v;
        }
    }
}

// ---------------- K3: depthwise causal conv1d (k=4) + bias + silu ----------
__global__ __launch_bounds__(256) void k_conv(const float* __restrict__ xin,
        const float* __restrict__ w, const float* __restrict__ bias,
        float* __restrict__ xc) {
    size_t idx = (size_t)blockIdx.x * 256 + threadIdx.x;
    int d = (int)(idx & (DI-1));
    size_t m = idx >> 9;
    int l = (int)(m & (L_-1));
    float acc = bias[d];
    #pragma unroll
    for (int k = 0; k < 4; ++k) {
        int t = l + k - 3;
        if (t >= 0)
            acc = fmaf(xin[idx + ((size_t)(k-3))*DI], w[d*4 + k], acc);
    }
    xc[idx] = acc * sigmoidf_(acc);
}

// ---------------- K4: x_proj v2 — tiled fp32 GEMM, M x 48, K=512 ----------
#define XBM 128
#define XBK 16
__global__ __launch_bounds__(256) void k_xproj(const float* __restrict__ xc,
        const float* __restrict__ wp, float* __restrict__ dbl) {
    __shared__ float As[XBK][XBM];   // 8 KB
    __shared__ float Ws[XBK][48];    // 3 KB
    int tid = threadIdx.x;
    int row0 = blockIdx.x * XBM;
    int lr = tid >> 1;
    int lk = (tid & 1) * 8;
    int we = tid >> 2;
    int wk = (tid & 3) * 4;
    int tx = tid & 15;
    int ty = tid >> 4;
    float acc[8][3];
    #pragma unroll
    for (int i = 0; i < 8; ++i)
        #pragma unroll
        for (int j = 0; j < 3; ++j) acc[i][j] = 0.f;

    for (int k0 = 0; k0 < DI; k0 += XBK) {
        float4 a0 = *(const float4*)(xc + (size_t)(row0+lr)*DI + k0 + lk);
        float4 a1 = *(const float4*)(xc + (size_t)(row0+lr)*DI + k0 + lk + 4);
        float4 w0 = make_float4(0.f,0.f,0.f,0.f);
        if (tid < 192) w0 = *(const float4*)(wp + (size_t)we*DI + k0 + wk);
        __syncthreads();
        As[lk+0][lr]=a0.x; As[lk+1][lr]=a0.y; As[lk+2][lr]=a0.z; As[lk+3][lr]=a0.w;
        As[lk+4][lr]=a1.x; As[lk+5][lr]=a1.y; As[lk+6][lr]=a1.z; As[lk+7][lr]=a1.w;
        if (tid < 192) {
            Ws[wk+0][we]=w0.x; Ws[wk+1][we]=w0.y; Ws[wk+2][we]=w0.z; Ws[wk+3][we]=w0.w;
        }
        __syncthreads();
        #pragma unroll
        for (int k = 0; k < XBK; ++k) {
            float4 av0 = *(const float4*)&As[k][ty*8];
            float4 av1 = *(const float4*)&As[k][ty*8+4];
            float w0_ = Ws[k][tx*3+0];
            float w1_ = Ws[k][tx*3+1];
            float w2_ = Ws[k][tx*3+2];
            float ar[8] = {av0.x,av0.y,av0.z,av0.w,av1.x,av1.y,av1.z,av1.w};
            #pragma unroll
            for (int i = 0; i < 8; ++i) {
                acc[i][0] = fmaf(ar[i], w0_, acc[i][0]);
                acc[i][1] = fmaf(ar[i], w1_, acc[i][1]);
                acc[i][2] = fmaf(ar[i], w2_, acc[i][2]);
            }
        }
    }
    #pragma unroll
    for (int i = 0; i < 8; ++i) {
        size_t r = row0 + ty*8 + i;
        #pragma unroll
        for (int j = 0; j < 3; ++j)
            dbl[r*48 + tx*3 + j] = acc[i][j];
    }
}

// ---------------- K5: dt_proj (K=16) + softplus ----------------------------
__global__ __launch_bounds__(256) void k_dtproj(const float* __restrict__ dbl,
        const float* __restrict__ dtw, const float* __restrict__ dtb,
        float* __restrict__ dt) {
    __shared__ float wl[DI][17];
    __shared__ float rl[32][16];
    size_t m0 = (size_t)blockIdx.x * 32;
    for (int i = threadIdx.x; i < DI*16; i += 256)
        wl[i >> 4][i & 15] = dtw[i];
    for (int i = threadIdx.x; i < 32*16; i += 256)
        rl[i >> 4][i & 15] = dbl[(m0 + (i>>4))*48 + (i & 15)];
    __syncthreads();
    float b0 = dtb[threadIdx.x];
    float b1 = dtb[256 + threadIdx.x];
    for (int mm = 0; mm < 32; ++mm) {
        #pragma unroll
        for (int half = 0; half < 2; ++half) {
            int d = half*256 + threadIdx.x;
            float acc = half ? b1 : b0;
            #pragma unroll
            for (int r = 0; r < 16; ++r)
                acc = fmaf(rl[mm][r], wl[d][r], acc);
            float sp = fmaxf(acc, 0.f) + log1pf(__expf(-fabsf(acc)));
            dt[(m0+mm)*DI + d] = sp;
        }
    }
}

// ---------------- K6: selective scan v4 — DPP reduce + direct y store ------
// 16 lanes per channel (one per state), 256 thr = 16 channels, grid 32x32.
// Reduction on VALU pipe (DPP); y stored straight to global by lane n==0
// (DS pipe freed: 36cy/t2 vs 76cy with shuffles+LDS transpose).
#define SCAN_T 64
__global__ __launch_bounds__(256) void k_scan(const float* __restrict__ dt,
        const float* __restrict__ xc, const float* __restrict__ dbl,
        const float* __restrict__ A_log, const float* __restrict__ Dp,
        const float* __restrict__ z, float* __restrict__ yb) {
    __shared__ float4 sq4[SCAN_T*17];     // [t][ch]: dt, dt*x, x*D*gate, gate
    __shared__ float2 sBC2[SCAN_T*17];    // [t][n]: B(t), C(t)

    int tid = threadIdx.x;
    int ch = tid >> 4;              // channel within block
    int n  = tid & 15;              // state index
    int d0 = blockIdx.x * 16;
    int b  = blockIdx.y;
    int d  = d0 + ch;
    float Avl2 = -expf(A_log[(size_t)d*NST + n]) * 1.44269504f;
    float h = 0.f;
    size_t base = (size_t)b * L_;

    int st = tid >> 2;
    int sc = (tid & 3) * 4;
    float4 Dv = *(const float4*)(Dp + d0 + sc);

    for (int t0 = 0; t0 < L_; t0 += SCAN_T) {
        __syncthreads();   // (A) compute reads done before LDS overwrite
        {
            size_t row = base + t0 + st;
            float4 dtv = *(const float4*)(dt + row*DI + d0 + sc);
            float4 xv  = *(const float4*)(xc + row*DI + d0 + sc);
            float4 zv  = *(const float4*)(z  + row*DI + d0 + sc);
            float4 Bv  = *(const float4*)(dbl + row*48 + 16 + sc);
            float4 Cv  = *(const float4*)(dbl + row*48 + 32 + sc);
            float g0 = zv.x * sigmoidf_(zv.x);
            float g1 = zv.y * sigmoidf_(zv.y);
            float g2 = zv.z * sigmoidf_(zv.z);
            float g3 = zv.w * sigmoidf_(zv.w);
            sq4[st*17 + sc+0] = make_float4(dtv.x, dtv.x*xv.x, xv.x*Dv.x*g0, g0);
            sq4[st*17 + sc+1] = make_float4(dtv.y, dtv.y*xv.y, xv.y*Dv.y*g1, g1);
            sq4[st*17 + sc+2] = make_float4(dtv.z, dtv.z*xv.z, xv.z*Dv.z*g2, g2);
            sq4[st*17 + sc+3] = make_float4(dtv.w, dtv.w*xv.w, xv.w*Dv.w*g3, g3);
            sBC2[st*17 + sc+0] = make_float2(Bv.x, Cv.x);
            sBC2[st*17 + sc+1] = make_float2(Bv.y, Cv.y);
            sBC2[st*17 + sc+2] = make_float2(Bv.z, Cv.z);
            sBC2[st*17 + sc+3] = make_float2(Bv.w, Cv.w);
        }
        __syncthreads();   // (B)

        #pragma unroll 2
        for (int t2 = 0; t2 < SCAN_T/2; ++t2) {
            float2 bc0 = sBC2[(2*t2)*17 + n];
            float2 bc1 = sBC2[(2*t2+1)*17 + n];
            float4 q0 = sq4[(2*t2)*17 + ch];
            float4 q1 = sq4[(2*t2+1)*17 + ch];
            // even step
            float dA = exp2f(q0.x * Avl2);
            h = fmaf(dA, h, q0.y * bc0.x);
            float p0 = h * bc0.y;
            // odd step
            dA = exp2f(q1.x * Avl2);
            h = fmaf(dA, h, q1.y * bc1.x);
            float p1 = h * bc1.y;
            reduce16_pair(p0, p1);          // all 16 lanes now hold the sums
            if (n == 0) {
                size_t row = base + t0 + 2*t2;
                yb[row*DI + d]      = fmaf(p0, q0.w, q0.z);
                yb[(row+1)*DI + d]  = fmaf(p1, q1.w, q1.z);
            }
        }
    }
}

// ---------------- K8: fused LayerNorm + silu + attn-max + class logits -----
__global__ __launch_bounds__(256) void k_lnheads(const float* __restrict__ m,
        const float* __restrict__ g, const float* __restrict__ bta,
        const float* __restrict__ aw, const float* __restrict__ ab,
        const float* __restrict__ ow, float* __restrict__ smax,
        float* __restrict__ logits) {
    __shared__ float sm[4];
    __shared__ float red[18][4];
    __shared__ float fin[18];
    size_t row = blockIdx.x;
    int tid = threadIdx.x;
    int wv = tid >> 6;
    int lane = tid & 63;
    float v = m[row*DM + tid];
    float s = v;
    #pragma unroll
    for (int o = 32; o > 0; o >>= 1) s += __shfl_xor(s, o);
    if (lane == 0) sm[wv] = s;
    __syncthreads();
    float mu = (sm[0]+sm[1]+sm[2]+sm[3]) * (1.0f/DM);
    __syncthreads();
    float c = v - mu;
    float s2 = c*c;
    #pragma unroll
    for (int o = 32; o > 0; o >>= 1) s2 += __shfl_xor(s2, o);
    if (lane == 0) sm[wv] = s2;
    __syncthreads();
    float var = (sm[0]+sm[1]+sm[2]+sm[3]) * (1.0f/DM);
    float o = c * (1.0f/sqrtf(var + 1e-5f)) * g[tid] + bta[tid];
    float ov = o * sigmoidf_(o);
    #pragma unroll
    for (int j = 0; j < NH+NC; ++j) {
        const float* wr = (j < NH) ? (aw + j*DM) : (ow + (j-NH)*DM);
        float p = ov * wr[tid];
        #pragma unroll
        for (int off = 32; off > 0; off >>= 1) p += __shfl_xor(p, off);
        if (lane == 0) red[j][wv] = p;
    }
    __syncthreads();
    if (tid < 18)
        fin[tid] = red[tid][0]+red[tid][1]+red[tid][2]+red[tid][3];
    __syncthreads();
    if (tid == 0) {
        float mx = fin[0] + ab[0];
        #pragma unroll
        for (int j = 1; j < NH; ++j) mx = fmaxf(mx, fin[j] + ab[j]);
        smax[row] = mx;
    }
    if (tid >= 8 && tid < 18)
        logits[row*NC + (tid-8)] = fin[tid];
}

// ---------------- K9b: per-b softmax over L + weighted logit sum -----------
__global__ __launch_bounds__(256) void k_final(const float* __restrict__ smax,
        const float* __restrict__ logits, const float* __restrict__ xmark,
        float* __restrict__ out) {
    __shared__ float e[L_];
    __shared__ float red[256];
    int b = blockIdx.x;
    int tid = threadIdx.x;
    float mx = -1e30f;
    for (int l = tid; l < L_; l += 256) {
        float s = smax[(size_t)b*L_ + l];
        e[l] = s;
        mx = fmaxf(mx, s);
    }
    #pragma unroll
    for (int o = 32; o > 0; o >>= 1) mx = fmaxf(mx, __shfl_xor(mx, o));
    red[tid] = mx;
    __syncthreads();
    mx = fmaxf(fmaxf(red[0], red[64]), fmaxf(red[128], red[192]));
    __syncthreads();
    float ssum = 0.f;
    for (int l = tid; l < L_; l += 256) {
        float ev = __expf(e[l] - mx);
        e[l] = ev;
        ssum += ev;
    }
    #pragma unroll
    for (int o = 32; o > 0; o >>= 1) ssum += __shfl_xor(ssum, o);
    if ((tid & 63) == 0) red[tid >> 6] = ssum;
    __syncthreads();
    float inv = 1.0f / (red[0]+red[1]+red[2]+red[3]);
    float acc[NC];
    #pragma unroll
    for (int c = 0; c < NC; ++c) acc[c] = 0.f;
    for (int l = tid; l < L_; l += 256) {
        float wl = e[l] * xmark[(size_t)b*L_ + l];
        const float* lg = logits + ((size_t)b*L_ + l)*NC;
        #pragma unroll
        for (int c = 0; c < NC; ++c) acc[c] = fmaf(wl, lg[c], acc[c]);
    }
    __syncthreads();
    for (int c = 0; c < NC; ++c) {
        red[tid] = acc[c];
        __syncthreads();
        if (tid < 64) {
            float s2 = red[tid]+red[tid+64]+red[tid+128]+red[tid+192];
            #pragma unroll
            for (int o = 32; o > 0; o >>= 1) s2 += __shfl_xor(s2, o);
            if (tid == 0) out[(size_t)b*NC + c] = s2 * inv;
        }
        __syncthreads();
    }
}

extern "C" void kernel_launch(void* const* d_in, const int* in_sizes, int n_in,
                              void* d_out, int out_size, void* d_ws, size_t ws_size,
                              hipStream_t stream) {
    const float* x_enc  = (const float*)d_in[0];
    const float* x_mark = (const float*)d_in[1];
    const float* cemb_w = (const float*)d_in[2];
    const float* inp_w  = (const float*)d_in[3];
    const float* c1_w   = (const float*)d_in[4];
    const float* c1_b   = (const float*)d_in[5];
    const float* xp_w   = (const float*)d_in[6];
    const float* dtp_w  = (const float*)d_in[7];
    const float* dtp_b  = (const float*)d_in[8];
    const float* A_log  = (const float*)d_in[9];
    const float* Dp     = (const float*)d_in[10];
    const float* outp_w = (const float*)d_in[11];
    const float* ln_g   = (const float*)d_in[12];
    const float* ln_b   = (const float*)d_in[13];
    const float* out_w  = (const float*)d_in[14];
    const float* attn_w = (const float*)d_in[15];
    const float* attn_b = (const float*)d_in[16];
    float* out = (float*)d_out;

    float* ws = (float*)d_ws;
    size_t o = 0;
    float* x    = ws + o; o += (size_t)M_TOT*DM;
    float* xin  = ws + o; o += (size_t)M_TOT*DI;
    float* z    = ws + o; o += (size_t)M_TOT*DI;
    float* xc   = ws + o; o += (size_t)M_TOT*DI;
    float* dbl  = ws + o; o += (size_t)M_TOT*48;
    float* smax = ws + o; o += (size_t)M_TOT;
    float* lgt  = ws + o; o += (size_t)M_TOT*NC;
    float* dt = xin;   // xin dead after k_conv
    float* yb = x;     // x dead after in_proj GEMM; scan output (y)
    float* mm = xc;    // xc dead after k_scan; out_proj output (m)

    k_embed <<<M_TOT, 256, 0, stream>>>(x_enc, cemb_w, x);
    k_gemm_nt<<<dim3(1024/BN, M_TOT/BM), 256, 0, stream>>>(x, inp_w, xin, z,
                                                           M_TOT, 1024, DM, DI);
    k_conv  <<<(M_TOT*DI)/256, 256, 0, stream>>>(xin, c1_w, c1_b, xc);
    k_xproj <<<M_TOT/XBM, 256, 0, stream>>>(xc, xp_w, dbl);
    k_dtproj<<<M_TOT/32, 256, 0, stream>>>(dbl, dtp_w, dtp_b, dt);
    k_scan  <<<dim3(DI/16, B_), 256, 0, stream>>>(dt, xc, dbl, A_log, Dp, z, yb);
    k_gemm_nt<<<dim3(DM/BN, M_TOT/BM), 256, 0, stream>>>(yb, outp_w, mm, mm,
                                                         M_TOT, DM, DI, DM);
    k_lnheads<<<M_TOT, 256, 0, stream>>>(mm, ln_g, ln_b, attn_w, attn_b,
                                         out_w, smax, lgt);
    k_final <<<B_, 256, 0, stream>>>(smax, lgt, x_mark, out);
}

// Round 9
// 629.729 us; speedup vs baseline: 2.6313x; 1.4413x over previous
//
#include <hip/hip_runtime.h>
#include <hip/hip_bf16.h>
#include <math.h>

#define B_  32
#define L_  1024
#define CIN 3
#define DM  256
#define DI  512
#define NST 16
#define NH  8
#define NC  10
#define M_TOT (B_*L_)

typedef unsigned short u16;
typedef __attribute__((ext_vector_type(8))) short bf16x8;
typedef __attribute__((ext_vector_type(4))) float f32x4;

static __device__ __forceinline__ float sigmoidf_(float x) {
    return 1.0f / (1.0f + __expf(-x));
}
static __device__ __forceinline__ u16 f2bf(float f) {       // RNE
    unsigned int u = __float_as_uint(f);
    return (u16)((u + 0x7FFF + ((u >> 16) & 1)) >> 16);
}
static __device__ __forceinline__ float bf2f(u16 u) {
    return __uint_as_float(((unsigned int)u) << 16);
}

// 16-lane sum via DPP (VALU pipe). s_nop guards VALU->DPP waitstates.
static __device__ __forceinline__ void reduce16_pair(float& a, float& b) {
    asm volatile(
        "s_nop 1\n\t"
        "v_add_f32 %0, %0, %0 quad_perm:[1,0,3,2] row_mask:0xf bank_mask:0xf\n\t"
        "v_add_f32 %1, %1, %1 quad_perm:[1,0,3,2] row_mask:0xf bank_mask:0xf\n\t"
        "s_nop 1\n\t"
        "v_add_f32 %0, %0, %0 quad_perm:[2,3,0,1] row_mask:0xf bank_mask:0xf\n\t"
        "v_add_f32 %1, %1, %1 quad_perm:[2,3,0,1] row_mask:0xf bank_mask:0xf\n\t"
        "s_nop 1\n\t"
        "v_add_f32 %0, %0, %0 row_ror:4 row_mask:0xf bank_mask:0xf\n\t"
        "v_add_f32 %1, %1, %1 row_ror:4 row_mask:0xf bank_mask:0xf\n\t"
        "s_nop 1\n\t"
        "v_add_f32 %0, %0, %0 row_ror:8 row_mask:0xf bank_mask:0xf\n\t"
        "v_add_f32 %1, %1, %1 row_ror:8 row_mask:0xf bank_mask:0xf\n\t"
        "s_nop 1\n\t"
        : "+v"(a), "+v"(b));
}

// ---------------- K0: fp32 -> bf16 weight conversion (n multiple of 1024) --
__global__ __launch_bounds__(256) void k_cvt(const float* __restrict__ in,
        u16* __restrict__ out) {
    int i = (blockIdx.x * 256 + threadIdx.x) * 4;
    float4 v = *(const float4*)(in + i);
    ushort4 o;
    o.x = f2bf(v.x); o.y = f2bf(v.y); o.z = f2bf(v.z); o.w = f2bf(v.w);
    *(ushort4*)(out + i) = o;
}

// ---------------- K1: conv embedding + positional encoding (bf16 out) ------
__global__ __launch_bounds__(256) void k_embed(const float* __restrict__ xe,
        const float* __restrict__ w, u16* __restrict__ x) {
    int bl = blockIdx.x;
    int l = bl & (L_-1);
    int b = bl >> 10;
    int d = threadIdx.x;
    const float* xb = xe + (size_t)b * L_ * CIN;
    int t0 = l > 0 ? l-1 : 0;
    int t2 = l < L_-1 ? l+1 : L_-1;
    const float* w3 = w + d*9;
    float acc = 0.f;
    #pragma unroll
    for (int i = 0; i < 3; ++i) {
        acc += xb[t0*3+i] * w3[i*3+0];
        acc += xb[l *3+i] * w3[i*3+1];
        acc += xb[t2*3+i] * w3[i*3+2];
    }
    int j = d >> 1;
    float div = expf((float)(2*j) * (-logf(10000.0f)/(float)DM));
    float ang = (float)l * div;
    acc += (d & 1) ? cosf(ang) : sinf(ang);
    x[(size_t)bl*DM + d] = f2bf(acc);
}

// ---------------- K2/K7: bf16 MFMA NT GEMM  C[m,n]=sum_k A[m,k]*W[n,k] -----
// A: M x K bf16 row-major; W: N x K bf16 row-major. 128x128 tile, BK=32,
// 256 thr = 4 waves (2x2 of 64x64; 4x4 fragments of 16x16 each).
// cols < S -> O1 fp32 (pitch S); cols >= S -> O2b bf16 (pitch N-S).
// LDS rows padded to 40 elems (80 B) -> conflict-free b128 reads.
#define GST 40
__global__ __launch_bounds__(256) void k_gemm_mfma(
        const u16* __restrict__ A, const u16* __restrict__ W,
        float* __restrict__ O1, u16* __restrict__ O2b,
        int M, int N, int K, int S) {
    __shared__ u16 As[128*GST];
    __shared__ u16 Bs[128*GST];
    int tid = threadIdx.x;
    int row0 = blockIdx.y * 128, col0 = blockIdx.x * 128;
    int wave = tid >> 6, lane = tid & 63;
    int wr = (wave >> 1) * 64, wc = (wave & 1) * 64;
    int l16 = lane & 15, kl = lane >> 4;
    int srow = tid >> 1, skh = (tid & 1) * 16;
    const u16* Ag = A + (size_t)(row0 + srow) * K + skh;
    const u16* Wg = W + (size_t)(col0 + srow) * K + skh;

    f32x4 acc[4][4];
    #pragma unroll
    for (int m = 0; m < 4; ++m)
        #pragma unroll
        for (int n = 0; n < 4; ++n)
            acc[m][n] = (f32x4){0.f, 0.f, 0.f, 0.f};

    for (int k0 = 0; k0 < K; k0 += 32) {
        uint4 a0 = *(const uint4*)(Ag + k0);
        uint4 a1 = *(const uint4*)(Ag + k0 + 8);
        uint4 b0 = *(const uint4*)(Wg + k0);
        uint4 b1 = *(const uint4*)(Wg + k0 + 8);
        __syncthreads();
        *(uint4*)&As[srow*GST + skh]     = a0;
        *(uint4*)&As[srow*GST + skh + 8] = a1;
        *(uint4*)&Bs[srow*GST + skh]     = b0;
        *(uint4*)&Bs[srow*GST + skh + 8] = b1;
        __syncthreads();
        bf16x8 af[4], bf[4];
        #pragma unroll
        for (int m = 0; m < 4; ++m)
            af[m] = *(const bf16x8*)&As[(wr + m*16 + l16)*GST + kl*8];
        #pragma unroll
        for (int n = 0; n < 4; ++n)
            bf[n] = *(const bf16x8*)&Bs[(wc + n*16 + l16)*GST + kl*8];
        #pragma unroll
        for (int m = 0; m < 4; ++m)
            #pragma unroll
            for (int n = 0; n < 4; ++n)
                acc[m][n] = __builtin_amdgcn_mfma_f32_16x16x32_bf16(
                                af[m], bf[n], acc[m][n], 0, 0, 0);
    }

    #pragma unroll
    for (int m = 0; m < 4; ++m) {
        int rbase = row0 + wr + m*16 + kl*4;
        #pragma unroll
        for (int n = 0; n < 4; ++n) {
            int col = col0 + wc + n*16 + l16;
            #pragma unroll
            for (int r = 0; r < 4; ++r) {
                float v = acc[m][n][r];
                if (col < S) O1[(size_t)(rbase + r)*S + col] = v;
                else         O2b[(size_t)(rbase + r)*(N - S) + (col - S)] = f2bf(v);
            }
        }
    }
}

// ---------------- K3: depthwise causal conv1d (k=4) + bias + silu ----------
__global__ __launch_bounds__(256) void k_conv(const float* __restrict__ xin,
        const float* __restrict__ w, const float* __restrict__ bias,
        float* __restrict__ xc) {
    size_t idx = (size_t)blockIdx.x * 256 + threadIdx.x;
    int d = (int)(idx & (DI-1));
    size_t m = idx >> 9;
    int l = (int)(m & (L_-1));
    float acc = bias[d];
    #pragma unroll
    for (int k = 0; k < 4; ++k) {
        int t = l + k - 3;
        if (t >= 0)
            acc = fmaf(xin[idx + ((size_t)(k-3))*DI], w[d*4 + k], acc);
    }
    xc[idx] = acc * sigmoidf_(acc);
}

// ---------------- K4: x_proj — tiled fp32 GEMM, M x 48, K=512 -------------
#define XBM 128
#define XBK 16
__global__ __launch_bounds__(256) void k_xproj(const float* __restrict__ xc,
        const float* __restrict__ wp, float* __restrict__ dbl) {
    __shared__ float As[XBK][XBM];
    __shared__ float Ws[XBK][48];
    int tid = threadIdx.x;
    int row0 = blockIdx.x * XBM;
    int lr = tid >> 1;
    int lk = (tid & 1) * 8;
    int we = tid >> 2;
    int wk = (tid & 3) * 4;
    int tx = tid & 15;
    int ty = tid >> 4;
    float acc[8][3];
    #pragma unroll
    for (int i = 0; i < 8; ++i)
        #pragma unroll
        for (int j = 0; j < 3; ++j) acc[i][j] = 0.f;

    for (int k0 = 0; k0 < DI; k0 += XBK) {
        float4 a0 = *(const float4*)(xc + (size_t)(row0+lr)*DI + k0 + lk);
        float4 a1 = *(const float4*)(xc + (size_t)(row0+lr)*DI + k0 + lk + 4);
        float4 w0 = make_float4(0.f,0.f,0.f,0.f);
        if (tid < 192) w0 = *(const float4*)(wp + (size_t)we*DI + k0 + wk);
        __syncthreads();
        As[lk+0][lr]=a0.x; As[lk+1][lr]=a0.y; As[lk+2][lr]=a0.z; As[lk+3][lr]=a0.w;
        As[lk+4][lr]=a1.x; As[lk+5][lr]=a1.y; As[lk+6][lr]=a1.z; As[lk+7][lr]=a1.w;
        if (tid < 192) {
            Ws[wk+0][we]=w0.x; Ws[wk+1][we]=w0.y; Ws[wk+2][we]=w0.z; Ws[wk+3][we]=w0.w;
        }
        __syncthreads();
        #pragma unroll
        for (int k = 0; k < XBK; ++k) {
            float4 av0 = *(const float4*)&As[k][ty*8];
            float4 av1 = *(const float4*)&As[k][ty*8+4];
            float w0_ = Ws[k][tx*3+0];
            float w1_ = Ws[k][tx*3+1];
            float w2_ = Ws[k][tx*3+2];
            float ar[8] = {av0.x,av0.y,av0.z,av0.w,av1.x,av1.y,av1.z,av1.w};
            #pragma unroll
            for (int i = 0; i < 8; ++i) {
                acc[i][0] = fmaf(ar[i], w0_, acc[i][0]);
                acc[i][1] = fmaf(ar[i], w1_, acc[i][1]);
                acc[i][2] = fmaf(ar[i], w2_, acc[i][2]);
            }
        }
    }
    #pragma unroll
    for (int i = 0; i < 8; ++i) {
        size_t r = row0 + ty*8 + i;
        #pragma unroll
        for (int j = 0; j < 3; ++j)
            dbl[r*48 + tx*3 + j] = acc[i][j];
    }
}

// ---------------- K5: dt_proj (K=16) + softplus ----------------------------
__global__ __launch_bounds__(256) void k_dtproj(const float* __restrict__ dbl,
        const float* __restrict__ dtw, const float* __restrict__ dtb,
        float* __restrict__ dt) {
    __shared__ float wl[DI][17];
    __shared__ float rl[32][16];
    size_t m0 = (size_t)blockIdx.x * 32;
    for (int i = threadIdx.x; i < DI*16; i += 256)
        wl[i >> 4][i & 15] = dtw[i];
    for (int i = threadIdx.x; i < 32*16; i += 256)
        rl[i >> 4][i & 15] = dbl[(m0 + (i>>4))*48 + (i & 15)];
    __syncthreads();
    float b0 = dtb[threadIdx.x];
    float b1 = dtb[256 + threadIdx.x];
    for (int mm = 0; mm < 32; ++mm) {
        #pragma unroll
        for (int half = 0; half < 2; ++half) {
            int d = half*256 + threadIdx.x;
            float acc = half ? b1 : b0;
            #pragma unroll
            for (int r = 0; r < 16; ++r)
                acc = fmaf(rl[mm][r], wl[d][r], acc);
            float sp = fmaxf(acc, 0.f) + log1pf(__expf(-fabsf(acc)));
            dt[(m0+mm)*DI + d] = sp;
        }
    }
}

// ---------------- K6: selective scan — DPP reduce, bf16 z in / y out -------
#define SCAN_T 64
__global__ __launch_bounds__(256) void k_scan(const float* __restrict__ dt,
        const float* __restrict__ xc, const float* __restrict__ dbl,
        const float* __restrict__ A_log, const float* __restrict__ Dp,
        const u16* __restrict__ zbf, u16* __restrict__ ybf) {
    __shared__ float4 sq4[SCAN_T*17];     // [t][ch]: dt, dt*x, x*D*gate, gate
    __shared__ float2 sBC2[SCAN_T*17];    // [t][n]: B(t), C(t)

    int tid = threadIdx.x;
    int ch = tid >> 4;
    int n  = tid & 15;
    int d0 = blockIdx.x * 16;
    int b  = blockIdx.y;
    int d  = d0 + ch;
    float Avl2 = -expf(A_log[(size_t)d*NST + n]) * 1.44269504f;
    float h = 0.f;
    size_t base = (size_t)b * L_;

    int st = tid >> 2;
    int sc = (tid & 3) * 4;
    float4 Dv = *(const float4*)(Dp + d0 + sc);

    for (int t0 = 0; t0 < L_; t0 += SCAN_T) {
        __syncthreads();
        {
            size_t row = base + t0 + st;
            float4 dtv = *(const float4*)(dt + row*DI + d0 + sc);
            float4 xv  = *(const float4*)(xc + row*DI + d0 + sc);
            ushort4 zv4 = *(const ushort4*)(zbf + row*DI + d0 + sc);
            float4 Bv  = *(const float4*)(dbl + row*48 + 16 + sc);
            float4 Cv  = *(const float4*)(dbl + row*48 + 32 + sc);
            float z0 = bf2f(zv4.x), z1 = bf2f(zv4.y);
            float z2 = bf2f(zv4.z), z3 = bf2f(zv4.w);
            float g0 = z0 * sigmoidf_(z0);
            float g1 = z1 * sigmoidf_(z1);
            float g2 = z2 * sigmoidf_(z2);
            float g3 = z3 * sigmoidf_(z3);
            sq4[st*17 + sc+0] = make_float4(dtv.x, dtv.x*xv.x, xv.x*Dv.x*g0, g0);
            sq4[st*17 + sc+1] = make_float4(dtv.y, dtv.y*xv.y, xv.y*Dv.y*g1, g1);
            sq4[st*17 + sc+2] = make_float4(dtv.z, dtv.z*xv.z, xv.z*Dv.z*g2, g2);
            sq4[st*17 + sc+3] = make_float4(dtv.w, dtv.w*xv.w, xv.w*Dv.w*g3, g3);
            sBC2[st*17 + sc+0] = make_float2(Bv.x, Cv.x);
            sBC2[st*17 + sc+1] = make_float2(Bv.y, Cv.y);
            sBC2[st*17 + sc+2] = make_float2(Bv.z, Cv.z);
            sBC2[st*17 + sc+3] = make_float2(Bv.w, Cv.w);
        }
        __syncthreads();

        #pragma unroll 2
        for (int t2 = 0; t2 < SCAN_T/2; ++t2) {
            float2 bc0 = sBC2[(2*t2)*17 + n];
            float2 bc1 = sBC2[(2*t2+1)*17 + n];
            float4 q0 = sq4[(2*t2)*17 + ch];
            float4 q1 = sq4[(2*t2+1)*17 + ch];
            float dA = exp2f(q0.x * Avl2);
            h = fmaf(dA, h, q0.y * bc0.x);
            float p0 = h * bc0.y;
            dA = exp2f(q1.x * Avl2);
            h = fmaf(dA, h, q1.y * bc1.x);
            float p1 = h * bc1.y;
            reduce16_pair(p0, p1);
            if (n == 0) {
                size_t row = base + t0 + 2*t2;
                ybf[row*DI + d]     = f2bf(fmaf(p0, q0.w, q0.z));
                ybf[(row+1)*DI + d] = f2bf(fmaf(p1, q1.w, q1.z));
            }
        }
    }
}

// ---------------- K8: fused LayerNorm + silu + attn-max + class logits -----
__global__ __launch_bounds__(256) void k_lnheads(const float* __restrict__ m,
        const float* __restrict__ g, const float* __restrict__ bta,
        const float* __restrict__ aw, const float* __restrict__ ab,
        const float* __restrict__ ow, float* __restrict__ smax,
        float* __restrict__ logits) {
    __shared__ float sm[4];
    __shared__ float red[18][4];
    __shared__ float fin[18];
    size_t row = blockIdx.x;
    int tid = threadIdx.x;
    int wv = tid >> 6;
    int lane = tid & 63;
    float v = m[row*DM + tid];
    float s = v;
    #pragma unroll
    for (int o = 32; o > 0; o >>= 1) s += __shfl_xor(s, o);
    if (lane == 0) sm[wv] = s;
    __syncthreads();
    float mu = (sm[0]+sm[1]+sm[2]+sm[3]) * (1.0f/DM);
    __syncthreads();
    float c = v - mu;
    float s2 = c*c;
    #pragma unroll
    for (int o = 32; o > 0; o >>= 1) s2 += __shfl_xor(s2, o);
    if (lane == 0) sm[wv] = s2;
    __syncthreads();
    float var = (sm[0]+sm[1]+sm[2]+sm[3]) * (1.0f/DM);
    float o = c * (1.0f/sqrtf(var + 1e-5f)) * g[tid] + bta[tid];
    float ov = o * sigmoidf_(o);
    #pragma unroll
    for (int j = 0; j < NH+NC; ++j) {
        const float* wr = (j < NH) ? (aw + j*DM) : (ow + (j-NH)*DM);
        float p = ov * wr[tid];
        #pragma unroll
        for (int off = 32; off > 0; off >>= 1) p += __shfl_xor(p, off);
        if (lane == 0) red[j][wv] = p;
    }
    __syncthreads();
    if (tid < 18)
        fin[tid] = red[tid][0]+red[tid][1]+red[tid][2]+red[tid][3];
    __syncthreads();
    if (tid == 0) {
        float mx = fin[0] + ab[0];
        #pragma unroll
        for (int j = 1; j < NH; ++j) mx = fmaxf(mx, fin[j] + ab[j]);
        smax[row] = mx;
    }
    if (tid >= 8 && tid < 18)
        logits[row*NC + (tid-8)] = fin[tid];
}

// ---------------- K9b: per-b softmax over L + weighted logit sum -----------
__global__ __launch_bounds__(256) void k_final(const float* __restrict__ smax,
        const float* __restrict__ logits, const float* __restrict__ xmark,
        float* __restrict__ out) {
    __shared__ float e[L_];
    __shared__ float red[256];
    int b = blockIdx.x;
    int tid = threadIdx.x;
    float mx = -1e30f;
    for (int l = tid; l < L_; l += 256) {
        float s = smax[(size_t)b*L_ + l];
        e[l] = s;
        mx = fmaxf(mx, s);
    }
    #pragma unroll
    for (int o = 32; o > 0; o >>= 1) mx = fmaxf(mx, __shfl_xor(mx, o));
    red[tid] = mx;
    __syncthreads();
    mx = fmaxf(fmaxf(red[0], red[64]), fmaxf(red[128], red[192]));
    __syncthreads();
    float ssum = 0.f;
    for (int l = tid; l < L_; l += 256) {
        float ev = __expf(e[l] - mx);
        e[l] = ev;
        ssum += ev;
    }
    #pragma unroll
    for (int o = 32; o > 0; o >>= 1) ssum += __shfl_xor(ssum, o);
    if ((tid & 63) == 0) red[tid >> 6] = ssum;
    __syncthreads();
    float inv = 1.0f / (red[0]+red[1]+red[2]+red[3]);
    float acc[NC];
    #pragma unroll
    for (int c = 0; c < NC; ++c) acc[c] = 0.f;
    for (int l = tid; l < L_; l += 256) {
        float wl = e[l] * xmark[(size_t)b*L_ + l];
        const float* lg = logits + ((size_t)b*L_ + l)*NC;
        #pragma unroll
        for (int c = 0; c < NC; ++c) acc[c] = fmaf(wl, lg[c], acc[c]);
    }
    __syncthreads();
    for (int c = 0; c < NC; ++c) {
        red[tid] = acc[c];
        __syncthreads();
        if (tid < 64) {
            float s2 = red[tid]+red[tid+64]+red[tid+128]+red[tid+192];
            #pragma unroll
            for (int o = 32; o > 0; o >>= 1) s2 += __shfl_xor(s2, o);
            if (tid == 0) out[(size_t)b*NC + c] = s2 * inv;
        }
        __syncthreads();
    }
}

extern "C" void kernel_launch(void* const* d_in, const int* in_sizes, int n_in,
                              void* d_out, int out_size, void* d_ws, size_t ws_size,
                              hipStream_t stream) {
    const float* x_enc  = (const float*)d_in[0];
    const float* x_mark = (const float*)d_in[1];
    const float* cemb_w = (const float*)d_in[2];
    const float* inp_w  = (const float*)d_in[3];
    const float* c1_w   = (const float*)d_in[4];
    const float* c1_b   = (const float*)d_in[5];
    const float* xp_w   = (const float*)d_in[6];
    const float* dtp_w  = (const float*)d_in[7];
    const float* dtp_b  = (const float*)d_in[8];
    const float* A_log  = (const float*)d_in[9];
    const float* Dp     = (const float*)d_in[10];
    const float* outp_w = (const float*)d_in[11];
    const float* ln_g   = (const float*)d_in[12];
    const float* ln_b   = (const float*)d_in[13];
    const float* out_w  = (const float*)d_in[14];
    const float* attn_w = (const float*)d_in[15];
    const float* attn_b = (const float*)d_in[16];
    float* out = (float*)d_out;

    char* ws = (char*)d_ws;
    size_t o = 0;
    u16*   xbf  = (u16*)(ws + o);  o += (size_t)M_TOT*DM*2;    // 16.8 MB
    float* xin  = (float*)(ws + o); o += (size_t)M_TOT*DI*4;   // 67 MB
    u16*   zbf  = (u16*)(ws + o);  o += (size_t)M_TOT*DI*2;    // 33.5 MB
    float* xc   = (float*)(ws + o); o += (size_t)M_TOT*DI*4;   // 67 MB
    u16*   ybf  = (u16*)(ws + o);  o += (size_t)M_TOT*DI*2;    // 33.5 MB
    float* dbl  = (float*)(ws + o); o += (size_t)M_TOT*48*4;   // 6.3 MB
    u16*   wbfi = (u16*)(ws + o);  o += (size_t)2*DI*DM*2;     // 0.5 MB
    u16*   wbfo = (u16*)(ws + o);  o += (size_t)DM*DI*2;       // 0.26 MB
    float* smax = (float*)(ws + o); o += (size_t)M_TOT*4;
    float* lgt  = (float*)(ws + o); o += (size_t)M_TOT*NC*4;
    float* dt = xin;   // xin dead after k_conv
    float* mm = xc;    // xc dead after k_scan; out_proj output

    k_cvt   <<<(2*DI*DM)/1024, 256, 0, stream>>>(inp_w, wbfi);
    k_cvt   <<<(DM*DI)/1024, 256, 0, stream>>>(outp_w, wbfo);
    k_embed <<<M_TOT, 256, 0, stream>>>(x_enc, cemb_w, xbf);
    k_gemm_mfma<<<dim3(8, M_TOT/128), 256, 0, stream>>>(xbf, wbfi, xin, zbf,
                                                        M_TOT, 2*DI, DM, DI);
    k_conv  <<<(M_TOT*DI)/256, 256, 0, stream>>>(xin, c1_w, c1_b, xc);
    k_xproj <<<M_TOT/XBM, 256, 0, stream>>>(xc, xp_w, dbl);
    k_dtproj<<<M_TOT/32, 256, 0, stream>>>(dbl, dtp_w, dtp_b, dt);
    k_scan  <<<dim3(DI/16, B_), 256, 0, stream>>>(dt, xc, dbl, A_log, Dp, zbf, ybf);
    k_gemm_mfma<<<dim3(2, M_TOT/128), 256, 0, stream>>>(ybf, wbfo, mm, zbf,
                                                        M_TOT, DM, DI, DM);
    k_lnheads<<<M_TOT, 256, 0, stream>>>(mm, ln_g, ln_b, attn_w, attn_b,
                                         out_w, smax, lgt);
    k_final <<<B_, 256, 0, stream>>>(smax, lgt, x_mark, out);
}

// Round 10
// 487.037 us; speedup vs baseline: 3.4023x; 1.2930x over previous
//
#include <hip/hip_runtime.h>
#include <hip/hip_bf16.h>
#include <math.h>

#define B_  32
#define L_  1024
#define CIN 3
#define DM  256
#define DI  512
#define NST 16
#define NH  8
#define NC  10
#define M_TOT (B_*L_)

typedef unsigned short u16;
typedef __attribute__((ext_vector_type(8))) short bf16x8;
typedef __attribute__((ext_vector_type(4))) float f32x4;

static __device__ __forceinline__ float sigmoidf_(float x) {
    return 1.0f / (1.0f + __expf(-x));
}
static __device__ __forceinline__ u16 f2bf(float f) {       // RNE
    unsigned int u = __float_as_uint(f);
    return (u16)((u + 0x7FFF + ((u >> 16) & 1)) >> 16);
}
static __device__ __forceinline__ float bf2f(u16 u) {
    return __uint_as_float(((unsigned int)u) << 16);
}

// 16-lane sum via DPP (VALU pipe). s_nop guards VALU->DPP waitstates.
static __device__ __forceinline__ void reduce16_pair(float& a, float& b) {
    asm volatile(
        "s_nop 1\n\t"
        "v_add_f32 %0, %0, %0 quad_perm:[1,0,3,2] row_mask:0xf bank_mask:0xf\n\t"
        "v_add_f32 %1, %1, %1 quad_perm:[1,0,3,2] row_mask:0xf bank_mask:0xf\n\t"
        "s_nop 1\n\t"
        "v_add_f32 %0, %0, %0 quad_perm:[2,3,0,1] row_mask:0xf bank_mask:0xf\n\t"
        "v_add_f32 %1, %1, %1 quad_perm:[2,3,0,1] row_mask:0xf bank_mask:0xf\n\t"
        "s_nop 1\n\t"
        "v_add_f32 %0, %0, %0 row_ror:4 row_mask:0xf bank_mask:0xf\n\t"
        "v_add_f32 %1, %1, %1 row_ror:4 row_mask:0xf bank_mask:0xf\n\t"
        "s_nop 1\n\t"
        "v_add_f32 %0, %0, %0 row_ror:8 row_mask:0xf bank_mask:0xf\n\t"
        "v_add_f32 %1, %1, %1 row_ror:8 row_mask:0xf bank_mask:0xf\n\t"
        "s_nop 1\n\t"
        : "+v"(a), "+v"(b));
}

// ---------------- K0: fp32 -> bf16 weight conversion -----------------------
__global__ __launch_bounds__(256) void k_cvt(const float* __restrict__ in,
        u16* __restrict__ out) {
    int i = (blockIdx.x * 256 + threadIdx.x) * 4;
    float4 v = *(const float4*)(in + i);
    ushort4 o;
    o.x = f2bf(v.x); o.y = f2bf(v.y); o.z = f2bf(v.z); o.w = f2bf(v.w);
    *(ushort4*)(out + i) = o;
}

// ---------------- K1: conv embedding + positional encoding (bf16 out) ------
__global__ __launch_bounds__(256) void k_embed(const float* __restrict__ xe,
        const float* __restrict__ w, u16* __restrict__ x) {
    int bl = blockIdx.x;
    int l = bl & (L_-1);
    int b = bl >> 10;
    int d = threadIdx.x;
    const float* xb = xe + (size_t)b * L_ * CIN;
    int t0 = l > 0 ? l-1 : 0;
    int t2 = l < L_-1 ? l+1 : L_-1;
    const float* w3 = w + d*9;
    float acc = 0.f;
    #pragma unroll
    for (int i = 0; i < 3; ++i) {
        acc += xb[t0*3+i] * w3[i*3+0];
        acc += xb[l *3+i] * w3[i*3+1];
        acc += xb[t2*3+i] * w3[i*3+2];
    }
    int j = d >> 1;
    float div = expf((float)(2*j) * (-logf(10000.0f)/(float)DM));
    float ang = (float)l * div;
    acc += (d & 1) ? cosf(ang) : sinf(ang);
    x[(size_t)bl*DM + d] = f2bf(acc);
}

// ---------------- K2/K7: bf16 MFMA NT GEMM ---------------------------------
#define GST 40
__global__ __launch_bounds__(256) void k_gemm_mfma(
        const u16* __restrict__ A, const u16* __restrict__ W,
        float* __restrict__ O1, u16* __restrict__ O2b,
        int M, int N, int K, int S) {
    __shared__ u16 As[128*GST];
    __shared__ u16 Bs[128*GST];
    int tid = threadIdx.x;
    int row0 = blockIdx.y * 128, col0 = blockIdx.x * 128;
    int wave = tid >> 6, lane = tid & 63;
    int wr = (wave >> 1) * 64, wc = (wave & 1) * 64;
    int l16 = lane & 15, kl = lane >> 4;
    int srow = tid >> 1, skh = (tid & 1) * 16;
    const u16* Ag = A + (size_t)(row0 + srow) * K + skh;
    const u16* Wg = W + (size_t)(col0 + srow) * K + skh;

    f32x4 acc[4][4];
    #pragma unroll
    for (int m = 0; m < 4; ++m)
        #pragma unroll
        for (int n = 0; n < 4; ++n)
            acc[m][n] = (f32x4){0.f, 0.f, 0.f, 0.f};

    for (int k0 = 0; k0 < K; k0 += 32) {
        uint4 a0 = *(const uint4*)(Ag + k0);
        uint4 a1 = *(const uint4*)(Ag + k0 + 8);
        uint4 b0 = *(const uint4*)(Wg + k0);
        uint4 b1 = *(const uint4*)(Wg + k0 + 8);
        __syncthreads();
        *(uint4*)&As[srow*GST + skh]     = a0;
        *(uint4*)&As[srow*GST + skh + 8] = a1;
        *(uint4*)&Bs[srow*GST + skh]     = b0;
        *(uint4*)&Bs[srow*GST + skh + 8] = b1;
        __syncthreads();
        bf16x8 af[4], bf[4];
        #pragma unroll
        for (int m = 0; m < 4; ++m)
            af[m] = *(const bf16x8*)&As[(wr + m*16 + l16)*GST + kl*8];
        #pragma unroll
        for (int n = 0; n < 4; ++n)
            bf[n] = *(const bf16x8*)&Bs[(wc + n*16 + l16)*GST + kl*8];
        #pragma unroll
        for (int m = 0; m < 4; ++m)
            #pragma unroll
            for (int n = 0; n < 4; ++n)
                acc[m][n] = __builtin_amdgcn_mfma_f32_16x16x32_bf16(
                                af[m], bf[n], acc[m][n], 0, 0, 0);
    }

    #pragma unroll
    for (int m = 0; m < 4; ++m) {
        int rbase = row0 + wr + m*16 + kl*4;
        #pragma unroll
        for (int n = 0; n < 4; ++n) {
            int col = col0 + wc + n*16 + l16;
            #pragma unroll
            for (int r = 0; r < 4; ++r) {
                float v = acc[m][n][r];
                if (col < S) O1[(size_t)(rbase + r)*S + col] = v;
                else         O2b[(size_t)(rbase + r)*(N - S) + (col - S)] = f2bf(v);
            }
        }
    }
}

// ---------------- K3: depthwise causal conv1d (k=4) + bias + silu ----------
__global__ __launch_bounds__(256) void k_conv(const float* __restrict__ xin,
        const float* __restrict__ w, const float* __restrict__ bias,
        float* __restrict__ xc) {
    size_t idx = (size_t)blockIdx.x * 256 + threadIdx.x;
    int d = (int)(idx & (DI-1));
    size_t m = idx >> 9;
    int l = (int)(m & (L_-1));
    float acc = bias[d];
    #pragma unroll
    for (int k = 0; k < 4; ++k) {
        int t = l + k - 3;
        if (t >= 0)
            acc = fmaf(xin[idx + ((size_t)(k-3))*DI], w[d*4 + k], acc);
    }
    xc[idx] = acc * sigmoidf_(acc);
}

// ---------------- K4: x_proj — tiled fp32 GEMM, M x 48, K=512 -------------
#define XBM 128
#define XBK 16
__global__ __launch_bounds__(256) void k_xproj(const float* __restrict__ xc,
        const float* __restrict__ wp, float* __restrict__ dbl) {
    __shared__ float As[XBK][XBM];
    __shared__ float Ws[XBK][48];
    int tid = threadIdx.x;
    int row0 = blockIdx.x * XBM;
    int lr = tid >> 1;
    int lk = (tid & 1) * 8;
    int we = tid >> 2;
    int wk = (tid & 3) * 4;
    int tx = tid & 15;
    int ty = tid >> 4;
    float acc[8][3];
    #pragma unroll
    for (int i = 0; i < 8; ++i)
        #pragma unroll
        for (int j = 0; j < 3; ++j) acc[i][j] = 0.f;

    for (int k0 = 0; k0 < DI; k0 += XBK) {
        float4 a0 = *(const float4*)(xc + (size_t)(row0+lr)*DI + k0 + lk);
        float4 a1 = *(const float4*)(xc + (size_t)(row0+lr)*DI + k0 + lk + 4);
        float4 w0 = make_float4(0.f,0.f,0.f,0.f);
        if (tid < 192) w0 = *(const float4*)(wp + (size_t)we*DI + k0 + wk);
        __syncthreads();
        As[lk+0][lr]=a0.x; As[lk+1][lr]=a0.y; As[lk+2][lr]=a0.z; As[lk+3][lr]=a0.w;
        As[lk+4][lr]=a1.x; As[lk+5][lr]=a1.y; As[lk+6][lr]=a1.z; As[lk+7][lr]=a1.w;
        if (tid < 192) {
            Ws[wk+0][we]=w0.x; Ws[wk+1][we]=w0.y; Ws[wk+2][we]=w0.z; Ws[wk+3][we]=w0.w;
        }
        __syncthreads();
        #pragma unroll
        for (int k = 0; k < XBK; ++k) {
            float4 av0 = *(const float4*)&As[k][ty*8];
            float4 av1 = *(const float4*)&As[k][ty*8+4];
            float w0_ = Ws[k][tx*3+0];
            float w1_ = Ws[k][tx*3+1];
            float w2_ = Ws[k][tx*3+2];
            float ar[8] = {av0.x,av0.y,av0.z,av0.w,av1.x,av1.y,av1.z,av1.w};
            #pragma unroll
            for (int i = 0; i < 8; ++i) {
                acc[i][0] = fmaf(ar[i], w0_, acc[i][0]);
                acc[i][1] = fmaf(ar[i], w1_, acc[i][1]);
                acc[i][2] = fmaf(ar[i], w2_, acc[i][2]);
            }
        }
    }
    #pragma unroll
    for (int i = 0; i < 8; ++i) {
        size_t r = row0 + ty*8 + i;
        #pragma unroll
        for (int j = 0; j < 3; ++j)
            dbl[r*48 + tx*3 + j] = acc[i][j];
    }
}

// ---------------- K5: dt_proj (K=16) + softplus ----------------------------
__global__ __launch_bounds__(256) void k_dtproj(const float* __restrict__ dbl,
        const float* __restrict__ dtw, const float* __restrict__ dtb,
        float* __restrict__ dt) {
    __shared__ float wl[DI][17];
    __shared__ float rl[32][16];
    size_t m0 = (size_t)blockIdx.x * 32;
    for (int i = threadIdx.x; i < DI*16; i += 256)
        wl[i >> 4][i & 15] = dtw[i];
    for (int i = threadIdx.x; i < 32*16; i += 256)
        rl[i >> 4][i & 15] = dbl[(m0 + (i>>4))*48 + (i & 15)];
    __syncthreads();
    float b0 = dtb[threadIdx.x];
    float b1 = dtb[256 + threadIdx.x];
    for (int mm = 0; mm < 32; ++mm) {
        #pragma unroll
        for (int half = 0; half < 2; ++half) {
            int d = half*256 + threadIdx.x;
            float acc = half ? b1 : b0;
            #pragma unroll
            for (int r = 0; r < 16; ++r)
                acc = fmaf(rl[mm][r], wl[d][r], acc);
            float sp = fmaxf(acc, 0.f) + log1pf(__expf(-fabsf(acc)));
            dt[(m0+mm)*DI + d] = sp;
        }
    }
}

// ---------------- K6: selective scan — DPP reduce, bf16 z in / y out -------
#define SCAN_T 64
__global__ __launch_bounds__(256) void k_scan(const float* __restrict__ dt,
        const float* __restrict__ xc, const float* __restrict__ dbl,
        const float* __restrict__ A_log, const float* __restrict__ Dp,
        const u16* __restrict__ zbf, u16* __restrict__ ybf) {
    __shared__ float4 sq4[SCAN_T*17];
    __shared__ float2 sBC2[SCAN_T*17];

    int tid = threadIdx.x;
    int ch = tid >> 4;
    int n  = tid & 15;
    int d0 = blockIdx.x * 16;
    int b  = blockIdx.y;
    int d  = d0 + ch;
    float Avl2 = -expf(A_log[(size_t)d*NST + n]) * 1.44269504f;
    float h = 0.f;
    size_t base = (size_t)b * L_;

    int st = tid >> 2;
    int sc = (tid & 3) * 4;
    float4 Dv = *(const float4*)(Dp + d0 + sc);

    for (int t0 = 0; t0 < L_; t0 += SCAN_T) {
        __syncthreads();
        {
            size_t row = base + t0 + st;
            float4 dtv = *(const float4*)(dt + row*DI + d0 + sc);
            float4 xv  = *(const float4*)(xc + row*DI + d0 + sc);
            ushort4 zv4 = *(const ushort4*)(zbf + row*DI + d0 + sc);
            float4 Bv  = *(const float4*)(dbl + row*48 + 16 + sc);
            float4 Cv  = *(const float4*)(dbl + row*48 + 32 + sc);
            float z0 = bf2f(zv4.x), z1 = bf2f(zv4.y);
            float z2 = bf2f(zv4.z), z3 = bf2f(zv4.w);
            float g0 = z0 * sigmoidf_(z0);
            float g1 = z1 * sigmoidf_(z1);
            float g2 = z2 * sigmoidf_(z2);
            float g3 = z3 * sigmoidf_(z3);
            sq4[st*17 + sc+0] = make_float4(dtv.x, dtv.x*xv.x, xv.x*Dv.x*g0, g0);
            sq4[st*17 + sc+1] = make_float4(dtv.y, dtv.y*xv.y, xv.y*Dv.y*g1, g1);
            sq4[st*17 + sc+2] = make_float4(dtv.z, dtv.z*xv.z, xv.z*Dv.z*g2, g2);
            sq4[st*17 + sc+3] = make_float4(dtv.w, dtv.w*xv.w, xv.w*Dv.w*g3, g3);
            sBC2[st*17 + sc+0] = make_float2(Bv.x, Cv.x);
            sBC2[st*17 + sc+1] = make_float2(Bv.y, Cv.y);
            sBC2[st*17 + sc+2] = make_float2(Bv.z, Cv.z);
            sBC2[st*17 + sc+3] = make_float2(Bv.w, Cv.w);
        }
        __syncthreads();

        #pragma unroll 2
        for (int t2 = 0; t2 < SCAN_T/2; ++t2) {
            float2 bc0 = sBC2[(2*t2)*17 + n];
            float2 bc1 = sBC2[(2*t2+1)*17 + n];
            float4 q0 = sq4[(2*t2)*17 + ch];
            float4 q1 = sq4[(2*t2+1)*17 + ch];
            float dA = exp2f(q0.x * Avl2);
            h = fmaf(dA, h, q0.y * bc0.x);
            float p0 = h * bc0.y;
            dA = exp2f(q1.x * Avl2);
            h = fmaf(dA, h, q1.y * bc1.x);
            float p1 = h * bc1.y;
            reduce16_pair(p0, p1);
            if (n == 0) {
                size_t row = base + t0 + 2*t2;
                ybf[row*DI + d]     = f2bf(fmaf(p0, q0.w, q0.z));
                ybf[(row+1)*DI + d] = f2bf(fmaf(p1, q1.w, q1.z));
            }
        }
    }
}

// ---------------- K8a: LayerNorm + silu, in place (1 wave = 1 row) ---------
__global__ __launch_bounds__(256) void k_lnsilu(float* __restrict__ m,
        const float* __restrict__ g, const float* __restrict__ bta) {
    size_t row = (size_t)blockIdx.x*4 + (threadIdx.x >> 6);
    int lane = threadIdx.x & 63;
    float4 v = *(const float4*)(m + row*DM + lane*4);
    float s = v.x + v.y + v.z + v.w;
    #pragma unroll
    for (int o = 32; o > 0; o >>= 1) s += __shfl_xor(s, o);
    float mu = s * (1.0f/DM);
    float4 c = make_float4(v.x-mu, v.y-mu, v.z-mu, v.w-mu);
    float s2 = c.x*c.x + c.y*c.y + c.z*c.z + c.w*c.w;
    #pragma unroll
    for (int o = 32; o > 0; o >>= 1) s2 += __shfl_xor(s2, o);
    float rstd = 1.0f / sqrtf(s2 * (1.0f/DM) + 1e-5f);
    float4 gv = *(const float4*)(g + lane*4);
    float4 bv = *(const float4*)(bta + lane*4);
    float o0 = c.x*rstd*gv.x + bv.x;
    float o1 = c.y*rstd*gv.y + bv.y;
    float o2 = c.z*rstd*gv.z + bv.z;
    float o3 = c.w*rstd*gv.w + bv.w;
    float4 r;
    r.x = o0 * sigmoidf_(o0);
    r.y = o1 * sigmoidf_(o1);
    r.z = o2 * sigmoidf_(o2);
    r.w = o3 * sigmoidf_(o3);
    *(float4*)(m + row*DM + lane*4) = r;
}

// ---------------- K8b: 18-col fp32 GEMM (8 heads + 10 classes), K=256 ------
// 128 rows/block; thread = (row=tid>>1, 9-col half=tid&1). LDS [.][36] rows
// (144B, 16B-aligned). Weight reads broadcast; A reads 4-way worst case.
#define HBK 32
__global__ __launch_bounds__(256) void k_heads18(const float* __restrict__ m,
        const float* __restrict__ aw, const float* __restrict__ ow,
        float* __restrict__ r18) {
    __shared__ float As[128][36];
    __shared__ float Ws[18][36];
    int tid = threadIdx.x;
    int row0 = blockIdx.x * 128;
    int r = tid >> 1, ch = tid & 1, cb = ch * 9;
    int sr = tid >> 1, sk = (tid & 1) * 16;
    float acc[9];
    #pragma unroll
    for (int c = 0; c < 9; ++c) acc[c] = 0.f;

    for (int k0 = 0; k0 < DM; k0 += HBK) {
        float4 a[4];
        #pragma unroll
        for (int q = 0; q < 4; ++q)
            a[q] = *(const float4*)(m + (size_t)(row0+sr)*DM + k0 + sk + q*4);
        float4 wv = make_float4(0.f,0.f,0.f,0.f);
        int wc = tid >> 3, wk = (tid & 7) * 4;   // tid<144: 18 rows x 8 quads
        if (tid < 144) {
            const float* wsrc = (wc < NH) ? (aw + wc*DM) : (ow + (wc-NH)*DM);
            wv = *(const float4*)(wsrc + k0 + wk);
        }
        __syncthreads();
        #pragma unroll
        for (int q = 0; q < 4; ++q)
            *(float4*)&As[sr][sk + q*4] = a[q];
        if (tid < 144)
            *(float4*)&Ws[wc][wk] = wv;
        __syncthreads();
        #pragma unroll
        for (int k4 = 0; k4 < HBK/4; ++k4) {
            float4 av = *(const float4*)&As[r][k4*4];
            #pragma unroll
            for (int c = 0; c < 9; ++c) {
                float4 w4 = *(const float4*)&Ws[cb + c][k4*4];
                acc[c] += av.x*w4.x + av.y*w4.y + av.z*w4.z + av.w*w4.w;
            }
        }
        __syncthreads();
    }
    #pragma unroll
    for (int c = 0; c < 9; ++c)
        r18[(size_t)(row0 + r)*18 + cb + c] = acc[c];
}

// ---------------- K9b: per-b head-max softmax over L + weighted logit sum --
__global__ __launch_bounds__(256) void k_final(const float* __restrict__ r18,
        const float* __restrict__ ab, const float* __restrict__ xmark,
        float* __restrict__ out) {
    __shared__ float e[L_];
    __shared__ float red[256];
    int b = blockIdx.x;
    int tid = threadIdx.x;
    float abr[NH];
    #pragma unroll
    for (int j = 0; j < NH; ++j) abr[j] = ab[j];
    float mx = -1e30f;
    for (int l = tid; l < L_; l += 256) {
        const float* rr = r18 + ((size_t)b*L_ + l)*18;
        float sm = rr[0] + abr[0];
        #pragma unroll
        for (int j = 1; j < NH; ++j) sm = fmaxf(sm, rr[j] + abr[j]);
        e[l] = sm;
        mx = fmaxf(mx, sm);
    }
    #pragma unroll
    for (int o = 32; o > 0; o >>= 1) mx = fmaxf(mx, __shfl_xor(mx, o));
    red[tid] = mx;
    __syncthreads();
    mx = fmaxf(fmaxf(red[0], red[64]), fmaxf(red[128], red[192]));
    __syncthreads();
    float ssum = 0.f;
    for (int l = tid; l < L_; l += 256) {
        float ev = __expf(e[l] - mx);
        e[l] = ev;
        ssum += ev;
    }
    #pragma unroll
    for (int o = 32; o > 0; o >>= 1) ssum += __shfl_xor(ssum, o);
    if ((tid & 63) == 0) red[tid >> 6] = ssum;
    __syncthreads();
    float inv = 1.0f / (red[0]+red[1]+red[2]+red[3]);
    float acc[NC];
    #pragma unroll
    for (int c = 0; c < NC; ++c) acc[c] = 0.f;
    for (int l = tid; l < L_; l += 256) {
        float wl = e[l] * xmark[(size_t)b*L_ + l];
        const float* lg = r18 + ((size_t)b*L_ + l)*18 + NH;
        #pragma unroll
        for (int c = 0; c < NC; ++c) acc[c] = fmaf(wl, lg[c], acc[c]);
    }
    __syncthreads();
    for (int c = 0; c < NC; ++c) {
        red[tid] = acc[c];
        __syncthreads();
        if (tid < 64) {
            float s2 = red[tid]+red[tid+64]+red[tid+128]+red[tid+192];
            #pragma unroll
            for (int o = 32; o > 0; o >>= 1) s2 += __shfl_xor(s2, o);
            if (tid == 0) out[(size_t)b*NC + c] = s2 * inv;
        }
        __syncthreads();
    }
}

extern "C" void kernel_launch(void* const* d_in, const int* in_sizes, int n_in,
                              void* d_out, int out_size, void* d_ws, size_t ws_size,
                              hipStream_t stream) {
    const float* x_enc  = (const float*)d_in[0];
    const float* x_mark = (const float*)d_in[1];
    const float* cemb_w = (const float*)d_in[2];
    const float* inp_w  = (const float*)d_in[3];
    const float* c1_w   = (const float*)d_in[4];
    const float* c1_b   = (const float*)d_in[5];
    const float* xp_w   = (const float*)d_in[6];
    const float* dtp_w  = (const float*)d_in[7];
    const float* dtp_b  = (const float*)d_in[8];
    const float* A_log  = (const float*)d_in[9];
    const float* Dp     = (const float*)d_in[10];
    const float* outp_w = (const float*)d_in[11];
    const float* ln_g   = (const float*)d_in[12];
    const float* ln_b   = (const float*)d_in[13];
    const float* out_w  = (const float*)d_in[14];
    const float* attn_w = (const float*)d_in[15];
    const float* attn_b = (const float*)d_in[16];
    float* out = (float*)d_out;

    char* ws = (char*)d_ws;
    size_t o = 0;
    u16*   xbf  = (u16*)(ws + o);  o += (size_t)M_TOT*DM*2;
    float* xin  = (float*)(ws + o); o += (size_t)M_TOT*DI*4;
    u16*   zbf  = (u16*)(ws + o);  o += (size_t)M_TOT*DI*2;
    float* xc   = (float*)(ws + o); o += (size_t)M_TOT*DI*4;
    u16*   ybf  = (u16*)(ws + o);  o += (size_t)M_TOT*DI*2;
    float* dbl  = (float*)(ws + o); o += (size_t)M_TOT*48*4;
    u16*   wbfi = (u16*)(ws + o);  o += (size_t)2*DI*DM*2;
    u16*   wbfo = (u16*)(ws + o);  o += (size_t)DM*DI*2;
    float* r18  = (float*)(ws + o); o += (size_t)M_TOT*18*4;
    float* dt = xin;   // xin dead after k_conv
    float* mm = xc;    // xc dead after k_scan; out_proj output

    k_cvt   <<<(2*DI*DM)/1024, 256, 0, stream>>>(inp_w, wbfi);
    k_cvt   <<<(DM*DI)/1024, 256, 0, stream>>>(outp_w, wbfo);
    k_embed <<<M_TOT, 256, 0, stream>>>(x_enc, cemb_w, xbf);
    k_gemm_mfma<<<dim3(8, M_TOT/128), 256, 0, stream>>>(xbf, wbfi, xin, zbf,
                                                        M_TOT, 2*DI, DM, DI);
    k_conv  <<<(M_TOT*DI)/256, 256, 0, stream>>>(xin, c1_w, c1_b, xc);
    k_xproj <<<M_TOT/XBM, 256, 0, stream>>>(xc, xp_w, dbl);
    k_dtproj<<<M_TOT/32, 256, 0, stream>>>(dbl, dtp_w, dtp_b, dt);
    k_scan  <<<dim3(DI/16, B_), 256, 0, stream>>>(dt, xc, dbl, A_log, Dp, zbf, ybf);
    k_gemm_mfma<<<dim3(2, M_TOT/128), 256, 0, stream>>>(ybf, wbfo, mm, zbf,
                                                        M_TOT, DM, DI, DM);
    k_lnsilu<<<M_TOT/4, 256, 0, stream>>>(mm, ln_g, ln_b);
    k_heads18<<<M_TOT/128, 256, 0, stream>>>(mm, attn_w, out_w, r18);
    k_final <<<B_, 256, 0, stream>>>(r18, attn_b, x_mark, out);
}

// Round 12
// 474.990 us; speedup vs baseline: 3.4886x; 1.0254x over previous
//
#include <hip/hip_runtime.h>
#include <hip/hip_bf16.h>
#include <math.h>

#define B_  32
#define L_  1024
#define CIN 3
#define DM  256
#define DI  512
#define NST 16
#define NH  8
#define NC  10
#define M_TOT (B_*L_)

typedef unsigned short u16;
typedef __attribute__((ext_vector_type(8))) short bf16x8;
typedef __attribute__((ext_vector_type(4))) float f32x4;

static __device__ __forceinline__ float sigmoidf_(float x) {
    return 1.0f / (1.0f + __expf(-x));
}
static __device__ __forceinline__ u16 f2bf(float f) {       // RNE
    unsigned int u = __float_as_uint(f);
    return (u16)((u + 0x7FFF + ((u >> 16) & 1)) >> 16);
}
static __device__ __forceinline__ float bf2f(u16 u) {
    return __uint_as_float(((unsigned int)u) << 16);
}

// 16-lane sum of 4 values via DPP (VALU pipe). 4-way interleave gives a
// 3-instruction gap between dependent DPP stages (>= required waitstates);
// single leading s_nop guards the immediately preceding VALU write.
static __device__ __forceinline__ void reduce16_quad(float& a, float& b,
                                                     float& c, float& d) {
    asm volatile(
        "s_nop 1\n\t"
        "v_add_f32 %0, %0, %0 quad_perm:[1,0,3,2] row_mask:0xf bank_mask:0xf\n\t"
        "v_add_f32 %1, %1, %1 quad_perm:[1,0,3,2] row_mask:0xf bank_mask:0xf\n\t"
        "v_add_f32 %2, %2, %2 quad_perm:[1,0,3,2] row_mask:0xf bank_mask:0xf\n\t"
        "v_add_f32 %3, %3, %3 quad_perm:[1,0,3,2] row_mask:0xf bank_mask:0xf\n\t"
        "v_add_f32 %0, %0, %0 quad_perm:[2,3,0,1] row_mask:0xf bank_mask:0xf\n\t"
        "v_add_f32 %1, %1, %1 quad_perm:[2,3,0,1] row_mask:0xf bank_mask:0xf\n\t"
        "v_add_f32 %2, %2, %2 quad_perm:[2,3,0,1] row_mask:0xf bank_mask:0xf\n\t"
        "v_add_f32 %3, %3, %3 quad_perm:[2,3,0,1] row_mask:0xf bank_mask:0xf\n\t"
        "v_add_f32 %0, %0, %0 row_ror:4 row_mask:0xf bank_mask:0xf\n\t"
        "v_add_f32 %1, %1, %1 row_ror:4 row_mask:0xf bank_mask:0xf\n\t"
        "v_add_f32 %2, %2, %2 row_ror:4 row_mask:0xf bank_mask:0xf\n\t"
        "v_add_f32 %3, %3, %3 row_ror:4 row_mask:0xf bank_mask:0xf\n\t"
        "v_add_f32 %0, %0, %0 row_ror:8 row_mask:0xf bank_mask:0xf\n\t"
        "v_add_f32 %1, %1, %1 row_ror:8 row_mask:0xf bank_mask:0xf\n\t"
        "v_add_f32 %2, %2, %2 row_ror:8 row_mask:0xf bank_mask:0xf\n\t"
        "v_add_f32 %3, %3, %3 row_ror:8 row_mask:0xf bank_mask:0xf\n\t"
        : "+v"(a), "+v"(b), "+v"(c), "+v"(d));
}

// ---------------- K0: fp32 -> bf16 weight conversion -----------------------
__global__ __launch_bounds__(256) void k_cvt(const float* __restrict__ in,
        u16* __restrict__ out) {
    int i = (blockIdx.x * 256 + threadIdx.x) * 4;
    float4 v = *(const float4*)(in + i);
    ushort4 o;
    o.x = f2bf(v.x); o.y = f2bf(v.y); o.z = f2bf(v.z); o.w = f2bf(v.w);
    *(ushort4*)(out + i) = o;
}

// ---------------- K1: conv embedding + positional encoding (bf16 out) ------
__global__ __launch_bounds__(256) void k_embed(const float* __restrict__ xe,
        const float* __restrict__ w, u16* __restrict__ x) {
    int bl = blockIdx.x;
    int l = bl & (L_-1);
    int b = bl >> 10;
    int d = threadIdx.x;
    const float* xb = xe + (size_t)b * L_ * CIN;
    int t0 = l > 0 ? l-1 : 0;
    int t2 = l < L_-1 ? l+1 : L_-1;
    const float* w3 = w + d*9;
    float acc = 0.f;
    #pragma unroll
    for (int i = 0; i < 3; ++i) {
        acc += xb[t0*3+i] * w3[i*3+0];
        acc += xb[l *3+i] * w3[i*3+1];
        acc += xb[t2*3+i] * w3[i*3+2];
    }
    int j = d >> 1;
    float div = expf((float)(2*j) * (-logf(10000.0f)/(float)DM));
    float ang = (float)l * div;
    acc += (d & 1) ? cosf(ang) : sinf(ang);
    x[(size_t)bl*DM + d] = f2bf(acc);
}

// ---------------- K2/K7: bf16 MFMA NT GEMM ---------------------------------
#define GST 40
__global__ __launch_bounds__(256) void k_gemm_mfma(
        const u16* __restrict__ A, const u16* __restrict__ W,
        float* __restrict__ O1, u16* __restrict__ O2b,
        int M, int N, int K, int S) {
    __shared__ u16 As[128*GST];
    __shared__ u16 Bs[128*GST];
    int tid = threadIdx.x;
    int row0 = blockIdx.y * 128, col0 = blockIdx.x * 128;
    int wave = tid >> 6, lane = tid & 63;
    int wr = (wave >> 1) * 64, wc = (wave & 1) * 64;
    int l16 = lane & 15, kl = lane >> 4;
    int srow = tid >> 1, skh = (tid & 1) * 16;
    const u16* Ag = A + (size_t)(row0 + srow) * K + skh;
    const u16* Wg = W + (size_t)(col0 + srow) * K + skh;

    f32x4 acc[4][4];
    #pragma unroll
    for (int m = 0; m < 4; ++m)
        #pragma unroll
        for (int n = 0; n < 4; ++n)
            acc[m][n] = (f32x4){0.f, 0.f, 0.f, 0.f};

    for (int k0 = 0; k0 < K; k0 += 32) {
        uint4 a0 = *(const uint4*)(Ag + k0);
        uint4 a1 = *(const uint4*)(Ag + k0 + 8);
        uint4 b0 = *(const uint4*)(Wg + k0);
        uint4 b1 = *(const uint4*)(Wg + k0 + 8);
        __syncthreads();
        *(uint4*)&As[srow*GST + skh]     = a0;
        *(uint4*)&As[srow*GST + skh + 8] = a1;
        *(uint4*)&Bs[srow*GST + skh]     = b0;
        *(uint4*)&Bs[srow*GST + skh + 8] = b1;
        __syncthreads();
        bf16x8 af[4], bf[4];
        #pragma unroll
        for (int m = 0; m < 4; ++m)
            af[m] = *(const bf16x8*)&As[(wr + m*16 + l16)*GST + kl*8];
        #pragma unroll
        for (int n = 0; n < 4; ++n)
            bf[n] = *(const bf16x8*)&Bs[(wc + n*16 + l16)*GST + kl*8];
        #pragma unroll
        for (int m = 0; m < 4; ++m)
            #pragma unroll
            for (int n = 0; n < 4; ++n)
                acc[m][n] = __builtin_amdgcn_mfma_f32_16x16x32_bf16(
                                af[m], bf[n], acc[m][n], 0, 0, 0);
    }

    #pragma unroll
    for (int m = 0; m < 4; ++m) {
        int rbase = row0 + wr + m*16 + kl*4;
        #pragma unroll
        for (int n = 0; n < 4; ++n) {
            int col = col0 + wc + n*16 + l16;
            #pragma unroll
            for (int r = 0; r < 4; ++r) {
                float v = acc[m][n][r];
                if (col < S) O1[(size_t)(rbase + r)*S + col] = v;
                else         O2b[(size_t)(rbase + r)*(N - S) + (col - S)] = f2bf(v);
            }
        }
    }
}

// ---------------- K3: depthwise causal conv1d (k=4) + bias + silu, x4 vec --
__global__ __launch_bounds__(256) void k_conv(const float* __restrict__ xin,
        const float* __restrict__ w, const float* __restrict__ bias,
        float* __restrict__ xc) {
    size_t i4 = (size_t)blockIdx.x * 256 + threadIdx.x;   // over M_TOT*DI/4
    int d4 = (int)(i4 & (DI/4 - 1)) * 4;
    size_t m = i4 >> 7;
    int l = (int)(m & (L_-1));
    float4 wv0 = *(const float4*)(w + (size_t)(d4+0)*4);
    float4 wv1 = *(const float4*)(w + (size_t)(d4+1)*4);
    float4 wv2 = *(const float4*)(w + (size_t)(d4+2)*4);
    float4 wv3 = *(const float4*)(w + (size_t)(d4+3)*4);
    float W[4][4] = {{wv0.x,wv0.y,wv0.z,wv0.w},{wv1.x,wv1.y,wv1.z,wv1.w},
                     {wv2.x,wv2.y,wv2.z,wv2.w},{wv3.x,wv3.y,wv3.z,wv3.w}};
    float4 acc = *(const float4*)(bias + d4);
    #pragma unroll
    for (int k = 0; k < 4; ++k) {
        int t = l + k - 3;
        if (t >= 0) {
            float4 xv = *(const float4*)(xin + (m + k - 3)*DI + d4);
            acc.x = fmaf(xv.x, W[0][k], acc.x);
            acc.y = fmaf(xv.y, W[1][k], acc.y);
            acc.z = fmaf(xv.z, W[2][k], acc.z);
            acc.w = fmaf(xv.w, W[3][k], acc.w);
        }
    }
    float4 r;
    r.x = acc.x * sigmoidf_(acc.x);
    r.y = acc.y * sigmoidf_(acc.y);
    r.z = acc.z * sigmoidf_(acc.z);
    r.w = acc.w * sigmoidf_(acc.w);
    *(float4*)(xc + m*DI + d4) = r;
}

// ---------------- K4: x_proj — tiled fp32 GEMM, M x 48, K=512 -------------
#define XBM 128
#define XBK 16
__global__ __launch_bounds__(256) void k_xproj(const float* __restrict__ xc,
        const float* __restrict__ wp, float* __restrict__ dbl) {
    __shared__ float As[XBK][XBM];
    __shared__ float Ws[XBK][48];
    int tid = threadIdx.x;
    int row0 = blockIdx.x * XBM;
    int lr = tid >> 1;
    int lk = (tid & 1) * 8;
    int we = tid >> 2;
    int wk = (tid & 3) * 4;
    int tx = tid & 15;
    int ty = tid >> 4;
    float acc[8][3];
    #pragma unroll
    for (int i = 0; i < 8; ++i)
        #pragma unroll
        for (int j = 0; j < 3; ++j) acc[i][j] = 0.f;

    for (int k0 = 0; k0 < DI; k0 += XBK) {
        float4 a0 = *(const float4*)(xc + (size_t)(row0+lr)*DI + k0 + lk);
        float4 a1 = *(const float4*)(xc + (size_t)(row0+lr)*DI + k0 + lk + 4);
        float4 w0 = make_float4(0.f,0.f,0.f,0.f);
        if (tid < 192) w0 = *(const float4*)(wp + (size_t)we*DI + k0 + wk);
        __syncthreads();
        As[lk+0][lr]=a0.x; As[lk+1][lr]=a0.y; As[lk+2][lr]=a0.z; As[lk+3][lr]=a0.w;
        As[lk+4][lr]=a1.x; As[lk+5][lr]=a1.y; As[lk+6][lr]=a1.z; As[lk+7][lr]=a1.w;
        if (tid < 192) {
            Ws[wk+0][we]=w0.x; Ws[wk+1][we]=w0.y; Ws[wk+2][we]=w0.z; Ws[wk+3][we]=w0.w;
        }
        __syncthreads();
        #pragma unroll
        for (int k = 0; k < XBK; ++k) {
            float4 av0 = *(const float4*)&As[k][ty*8];
            float4 av1 = *(const float4*)&As[k][ty*8+4];
            float w0_ = Ws[k][tx*3+0];
            float w1_ = Ws[k][tx*3+1];
            float w2_ = Ws[k][tx*3+2];
            float ar[8] = {av0.x,av0.y,av0.z,av0.w,av1.x,av1.y,av1.z,av1.w};
            #pragma unroll
            for (int i = 0; i < 8; ++i) {
                acc[i][0] = fmaf(ar[i], w0_, acc[i][0]);
                acc[i][1] = fmaf(ar[i], w1_, acc[i][1]);
                acc[i][2] = fmaf(ar[i], w2_, acc[i][2]);
            }
        }
    }
    #pragma unroll
    for (int i = 0; i < 8; ++i) {
        size_t r = row0 + ty*8 + i;
        #pragma unroll
        for (int j = 0; j < 3; ++j)
            dbl[r*48 + tx*3 + j] = acc[i][j];
    }
}

// ---------------- K5: dt_proj (K=16) + softplus ----------------------------
__global__ __launch_bounds__(256) void k_dtproj(const float* __restrict__ dbl,
        const float* __restrict__ dtw, const float* __restrict__ dtb,
        float* __restrict__ dt) {
    __shared__ float wl[DI][17];
    __shared__ float rl[32][16];
    size_t m0 = (size_t)blockIdx.x * 32;
    for (int i = threadIdx.x; i < DI*16; i += 256)
        wl[i >> 4][i & 15] = dtw[i];
    for (int i = threadIdx.x; i < 32*16; i += 256)
        rl[i >> 4][i & 15] = dbl[(m0 + (i>>4))*48 + (i & 15)];
    __syncthreads();
    float b0 = dtb[threadIdx.x];
    float b1 = dtb[256 + threadIdx.x];
    for (int mm = 0; mm < 32; ++mm) {
        #pragma unroll
        for (int half = 0; half < 2; ++half) {
            int d = half*256 + threadIdx.x;
            float acc = half ? b1 : b0;
            #pragma unroll
            for (int r = 0; r < 16; ++r)
                acc = fmaf(rl[mm][r], wl[d][r], acc);
            float sp = fmaxf(acc, 0.f) + log1pf(__expf(-fabsf(acc)));
            dt[(m0+mm)*DI + d] = sp;
        }
    }
}

// ---------------- K6: selective scan v5 — BC in regs, 4-step DPP quad ------
// 16 lanes/channel, 256 thr = 16 ch, grid (DI/16, B_). q staged in LDS;
// B,C loaded to registers per 16-step sub-chunk (L2-hot dbl broadcasts).
#define SCAN_T 64
__global__ __launch_bounds__(256) void k_scan(const float* __restrict__ dt,
        const float* __restrict__ xc, const float* __restrict__ dbl,
        const float* __restrict__ A_log, const float* __restrict__ Dp,
        const u16* __restrict__ zbf, u16* __restrict__ ybf) {
    __shared__ float4 sq4[SCAN_T*17];     // [t][ch]: dt, dt*x, x*D*gate, gate

    int tid = threadIdx.x;
    int ch = tid >> 4;
    int n  = tid & 15;
    int d0 = blockIdx.x * 16;
    int b  = blockIdx.y;
    int d  = d0 + ch;
    float Avl2 = -expf(A_log[(size_t)d*NST + n]) * 1.44269504f;
    float h = 0.f;
    size_t base = (size_t)b * L_;

    int st = tid >> 2;
    int sc = (tid & 3) * 4;
    float4 Dv = *(const float4*)(Dp + d0 + sc);

    for (int t0 = 0; t0 < L_; t0 += SCAN_T) {
        __syncthreads();
        {
            size_t row = base + t0 + st;
            float4 dtv = *(const float4*)(dt + row*DI + d0 + sc);
            float4 xv  = *(const float4*)(xc + row*DI + d0 + sc);
            ushort4 zv4 = *(const ushort4*)(zbf + row*DI + d0 + sc);
            float z0 = bf2f(zv4.x), z1 = bf2f(zv4.y);
            float z2 = bf2f(zv4.z), z3 = bf2f(zv4.w);
            float g0 = z0 * sigmoidf_(z0);
            float g1 = z1 * sigmoidf_(z1);
            float g2 = z2 * sigmoidf_(z2);
            float g3 = z3 * sigmoidf_(z3);
            sq4[st*17 + sc+0] = make_float4(dtv.x, dtv.x*xv.x, xv.x*Dv.x*g0, g0);
            sq4[st*17 + sc+1] = make_float4(dtv.y, dtv.y*xv.y, xv.y*Dv.y*g1, g1);
            sq4[st*17 + sc+2] = make_float4(dtv.z, dtv.z*xv.z, xv.z*Dv.z*g2, g2);
            sq4[st*17 + sc+3] = make_float4(dtv.w, dtv.w*xv.w, xv.w*Dv.w*g3, g3);
        }
        __syncthreads();

        for (int tt = 0; tt < SCAN_T; tt += 16) {
            float Br[16], Cr[16];
            #pragma unroll
            for (int j = 0; j < 16; ++j) {
                size_t r48 = (base + t0 + tt + j) * 48;
                Br[j] = dbl[r48 + 16 + n];
                Cr[j] = dbl[r48 + 32 + n];
            }
            #pragma unroll
            for (int j4 = 0; j4 < 4; ++j4) {
                int tb = tt + j4*4;
                float4 q0 = sq4[(tb+0)*17 + ch];
                float4 q1 = sq4[(tb+1)*17 + ch];
                float4 q2 = sq4[(tb+2)*17 + ch];
                float4 q3 = sq4[(tb+3)*17 + ch];
                float dA;
                dA = exp2f(q0.x * Avl2);
                h = fmaf(dA, h, q0.y * Br[j4*4+0]);
                float p0 = h * Cr[j4*4+0];
                dA = exp2f(q1.x * Avl2);
                h = fmaf(dA, h, q1.y * Br[j4*4+1]);
                float p1 = h * Cr[j4*4+1];
                dA = exp2f(q2.x * Avl2);
                h = fmaf(dA, h, q2.y * Br[j4*4+2]);
                float p2 = h * Cr[j4*4+2];
                dA = exp2f(q3.x * Avl2);
                h = fmaf(dA, h, q3.y * Br[j4*4+3]);
                float p3 = h * Cr[j4*4+3];
                reduce16_quad(p0, p1, p2, p3);
                if (n == 0) {
                    size_t row = base + t0 + tb;
                    ybf[(row+0)*DI + d] = f2bf(fmaf(p0, q0.w, q0.z));
                    ybf[(row+1)*DI + d] = f2bf(fmaf(p1, q1.w, q1.z));
                    ybf[(row+2)*DI + d] = f2bf(fmaf(p2, q2.w, q2.z));
                    ybf[(row+3)*DI + d] = f2bf(fmaf(p3, q3.w, q3.z));
                }
            }
        }
    }
}

// ---------------- K8a: LayerNorm + silu, in place (1 wave = 1 row) ---------
__global__ __launch_bounds__(256) void k_lnsilu(float* __restrict__ m,
        const float* __restrict__ g, const float* __restrict__ bta) {
    size_t row = (size_t)blockIdx.x*4 + (threadIdx.x >> 6);
    int lane = threadIdx.x & 63;
    float4 v = *(const float4*)(m + row*DM + lane*4);
    float s = v.x + v.y + v.z + v.w;
    #pragma unroll
    for (int o = 32; o > 0; o >>= 1) s += __shfl_xor(s, o);
    float mu = s * (1.0f/DM);
    float4 c = make_float4(v.x-mu, v.y-mu, v.z-mu, v.w-mu);
    float s2 = c.x*c.x + c.y*c.y + c.z*c.z + c.w*c.w;
    #pragma unroll
    for (int o = 32; o > 0; o >>= 1) s2 += __shfl_xor(s2, o);
    float rstd = 1.0f / sqrtf(s2 * (1.0f/DM) + 1e-5f);
    float4 gv = *(const float4*)(g + lane*4);
    float4 bv = *(const float4*)(bta + lane*4);
    float o0 = c.x*rstd*gv.x + bv.x;
    float o1 = c.y*rstd*gv.y + bv.y;
    float o2 = c.z*rstd*gv.z + bv.z;
    float o3 = c.w*rstd*gv.w + bv.w;
    float4 r;
    r.x = o0 * sigmoidf_(o0);
    r.y = o1 * sigmoidf_(o1);
    r.z = o2 * sigmoidf_(o2);
    r.w = o3 * sigmoidf_(o3);
    *(float4*)(m + row*DM + lane*4) = r;
}

// ---------------- K8b: 18-col fp32 GEMM (8 heads + 10 classes), K=256 ------
#define HBK 32
__global__ __launch_bounds__(256) void k_heads18(const float* __restrict__ m,
        const float* __restrict__ aw, const float* __restrict__ ow,
        float* __restrict__ r18) {
    __shared__ float As[128][36];
    __shared__ float Ws[18][36];
    int tid = threadIdx.x;
    int row0 = blockIdx.x * 128;
    int r = tid >> 1, ch = tid & 1, cb = ch * 9;
    int sr = tid >> 1, sk = (tid & 1) * 16;
    float acc[9];
    #pragma unroll
    for (int c = 0; c < 9; ++c) acc[c] = 0.f;

    for (int k0 = 0; k0 < DM; k0 += HBK) {
        float4 a[4];
        #pragma unroll
        for (int q = 0; q < 4; ++q)
            a[q] = *(const float4*)(m + (size_t)(row0+sr)*DM + k0 + sk + q*4);
        float4 wv = make_float4(0.f,0.f,0.f,0.f);
        int wc = tid >> 3, wk = (tid & 7) * 4;
        if (tid < 144) {
            const float* wsrc = (wc < NH) ? (aw + wc*DM) : (ow + (wc-NH)*DM);
            wv = *(const float4*)(wsrc + k0 + wk);
        }
        __syncthreads();
        #pragma unroll
        for (int q = 0; q < 4; ++q)
            *(float4*)&As[sr][sk + q*4] = a[q];
        if (tid < 144)
            *(float4*)&Ws[wc][wk] = wv;
        __syncthreads();
        #pragma unroll
        for (int k4 = 0; k4 < HBK/4; ++k4) {
            float4 av = *(const float4*)&As[r][k4*4];
            #pragma unroll
            for (int c = 0; c < 9; ++c) {
                float4 w4 = *(const float4*)&Ws[cb + c][k4*4];
                acc[c] += av.x*w4.x + av.y*w4.y + av.z*w4.z + av.w*w4.w;
            }
        }
        __syncthreads();
    }
    #pragma unroll
    for (int c = 0; c < 9; ++c)
        r18[(size_t)(row0 + r)*18 + cb + c] = acc[c];
}

// ---------------- K9b: per-b head-max softmax over L + weighted logit sum --
__global__ __launch_bounds__(256) void k_final(const float* __restrict__ r18,
        const float* __restrict__ ab, const float* __restrict__ xmark,
        float* __restrict__ out) {
    __shared__ float e[L_];
    __shared__ float red[256];
    int b = blockIdx.x;
    int tid = threadIdx.x;
    float abr[NH];
    #pragma unroll
    for (int j = 0; j < NH; ++j) abr[j] = ab[j];
    float mx = -1e30f;
    for (int l = tid; l < L_; l += 256) {
        const float* rr = r18 + ((size_t)b*L_ + l)*18;
        float sm = rr[0] + abr[0];
        #pragma unroll
        for (int j = 1; j < NH; ++j) sm = fmaxf(sm, rr[j] + abr[j]);
        e[l] = sm;
        mx = fmaxf(mx, sm);
    }
    #pragma unroll
    for (int o = 32; o > 0; o >>= 1) mx = fmaxf(mx, __shfl_xor(mx, o));
    red[tid] = mx;
    __syncthreads();
    mx = fmaxf(fmaxf(red[0], red[64]), fmaxf(red[128], red[192]));
    __syncthreads();
    float ssum = 0.f;
    for (int l = tid; l < L_; l += 256) {
        float ev = __expf(e[l] - mx);
        e[l] = ev;
        ssum += ev;
    }
    #pragma unroll
    for (int o = 32; o > 0; o >>= 1) ssum += __shfl_xor(ssum, o);
    if ((tid & 63) == 0) red[tid >> 6] = ssum;
    __syncthreads();
    float inv = 1.0f / (red[0]+red[1]+red[2]+red[3]);
    float acc[NC];
    #pragma unroll
    for (int c = 0; c < NC; ++c) acc[c] = 0.f;
    for (int l = tid; l < L_; l += 256) {
        float wl = e[l] * xmark[(size_t)b*L_ + l];
        const float* lg = r18 + ((size_t)b*L_ + l)*18 + NH;
        #pragma unroll
        for (int c = 0; c < NC; ++c) acc[c] = fmaf(wl, lg[c], acc[c]);
    }
    __syncthreads();
    for (int c = 0; c < NC; ++c) {
        red[tid] = acc[c];
        __syncthreads();
        if (tid < 64) {
            float s2 = red[tid]+red[tid+64]+red[tid+128]+red[tid+192];
            #pragma unroll
            for (int o = 32; o > 0; o >>= 1) s2 += __shfl_xor(s2, o);
            if (tid == 0) out[(size_t)b*NC + c] = s2 * inv;
        }
        __syncthreads();
    }
}

extern "C" void kernel_launch(void* const* d_in, const int* in_sizes, int n_in,
                              void* d_out, int out_size, void* d_ws, size_t ws_size,
                              hipStream_t stream) {
    const float* x_enc  = (const float*)d_in[0];
    const float* x_mark = (const float*)d_in[1];
    const float* cemb_w = (const float*)d_in[2];
    const float* inp_w  = (const float*)d_in[3];
    const float* c1_w   = (const float*)d_in[4];
    const float* c1_b   = (const float*)d_in[5];
    const float* xp_w   = (const float*)d_in[6];
    const float* dtp_w  = (const float*)d_in[7];
    const float* dtp_b  = (const float*)d_in[8];
    const float* A_log  = (const float*)d_in[9];
    const float* Dp     = (const float*)d_in[10];
    const float* outp_w = (const float*)d_in[11];
    const float* ln_g   = (const float*)d_in[12];
    const float* ln_b   = (const float*)d_in[13];
    const float* out_w  = (const float*)d_in[14];
    const float* attn_w = (const float*)d_in[15];
    const float* attn_b = (const float*)d_in[16];
    float* out = (float*)d_out;

    char* ws = (char*)d_ws;
    size_t o = 0;
    u16*   xbf  = (u16*)(ws + o);  o += (size_t)M_TOT*DM*2;
    float* xin  = (float*)(ws + o); o += (size_t)M_TOT*DI*4;
    u16*   zbf  = (u16*)(ws + o);  o += (size_t)M_TOT*DI*2;
    float* xc   = (float*)(ws + o); o += (size_t)M_TOT*DI*4;
    u16*   ybf  = (u16*)(ws + o);  o += (size_t)M_TOT*DI*2;
    float* dbl  = (float*)(ws + o); o += (size_t)M_TOT*48*4;
    u16*   wbfi = (u16*)(ws + o);  o += (size_t)2*DI*DM*2;
    u16*   wbfo = (u16*)(ws + o);  o += (size_t)DM*DI*2;
    float* r18  = (float*)(ws + o); o += (size_t)M_TOT*18*4;
    float* dt = xin;   // xin dead after k_conv
    float* mm = xc;    // xc dead after k_scan; out_proj output

    k_cvt   <<<(2*DI*DM)/1024, 256, 0, stream>>>(inp_w, wbfi);
    k_cvt   <<<(DM*DI)/1024, 256, 0, stream>>>(outp_w, wbfo);
    k_embed <<<M_TOT, 256, 0, stream>>>(x_enc, cemb_w, xbf);
    k_gemm_mfma<<<dim3(8, M_TOT/128), 256, 0, stream>>>(xbf, wbfi, xin, zbf,
                                                        M_TOT, 2*DI, DM, DI);
    k_conv  <<<(M_TOT*DI/4)/256, 256, 0, stream>>>(xin, c1_w, c1_b, xc);
    k_xproj <<<M_TOT/XBM, 256, 0, stream>>>(xc, xp_w, dbl);
    k_dtproj<<<M_TOT/32, 256, 0, stream>>>(dbl, dtp_w, dtp_b, dt);
    k_scan  <<<dim3(DI/16, B_), 256, 0, stream>>>(dt, xc, dbl, A_log, Dp, zbf, ybf);
    k_gemm_mfma<<<dim3(2, M_TOT/128), 256, 0, stream>>>(ybf, wbfo, mm, zbf,
                                                        M_TOT, DM, DI, DM);
    k_lnsilu<<<M_TOT/4, 256, 0, stream>>>(mm, ln_g, ln_b);
    k_heads18<<<M_TOT/128, 256, 0, stream>>>(mm, attn_w, out_w, r18);
    k_final <<<B_, 256, 0, stream>>>(r18, attn_b, x_mark, out);
}